// Round 1
// baseline (424.976 us; speedup 1.0000x reference)
//
#include <hip/hip_runtime.h>
#include <cstdint>

#define S_LEN 2048
#define BATCH 4
#define NHEADS 12
#define DHEAD 64
#define DMODEL 768

typedef unsigned short ushort_t;
typedef __attribute__((ext_vector_type(8))) __bf16 bf16x8;
typedef __attribute__((ext_vector_type(4))) float floatx4;

// fp32 -> bf16 round-to-nearest-even (values are finite; no NaN path needed)
__device__ __forceinline__ ushort_t f2bf(float f) {
  unsigned int u = __builtin_bit_cast(unsigned int, f);
  u += 0x7fffu + ((u >> 16) & 1u);
  return (ushort_t)(u >> 16);
}

// async global->LDS, 16B per lane. LDS dest is wave-uniform base + lane*16 (HW adds it).
__device__ __forceinline__ void gld16(const void* g, void* s) {
  __builtin_amdgcn_global_load_lds(
      (const __attribute__((address_space(1))) void*)g,
      (__attribute__((address_space(3))) void*)s, 16, 0, 0);
}

__device__ __forceinline__ floatx4 mfma16(bf16x8 a, bf16x8 b, floatx4 c) {
  return __builtin_amdgcn_mfma_f32_16x16x32_bf16(a, b, c, 0, 0, 0);
}

__global__ void init_flag(int* flag) { *flag = 1; }

__global__ void mask_check(const float* __restrict__ mask, int* __restrict__ flag) {
  int i = blockIdx.x * 256 + threadIdx.x;  // grid sized exactly: S*S/4 threads
  float4 v = ((const float4*)mask)[i];
  if (v.x != 0.f || v.y != 0.f || v.z != 0.f || v.w != 0.f) *flag = 0;
}

__global__ void cvt_bf16(const float* __restrict__ src, ushort_t* __restrict__ dst, int n4) {
  int i = blockIdx.x * 256 + threadIdx.x;
  if (i < n4) {
    float4 v = ((const float4*)src)[i];
    ushort4 o;
    o.x = f2bf(v.x); o.y = f2bf(v.y); o.z = f2bf(v.z); o.w = f2bf(v.w);
    ((ushort4*)dst)[i] = o;
  }
}

// C[M,N] = A[M,K] @ B[N,K]^T + bias[n], bf16 inputs, fp32 accumulate.
// 128x128 tile, BK=32, 4 waves in 2x2, each wave 64x64 via 4x4 of 16x16x32 MFMA.
// MODE 0: scatter Q->(B,H,S,Dh) bf16.  MODE 1: split KV -> K(B,H,S,Dh), V^T(B,H,Dh,S) bf16.
// MODE 2: fp32 out row-major [M,N].
template <int MODE>
__global__ __launch_bounds__(256, 2) void gemm_bt(
    const ushort_t* __restrict__ A, const ushort_t* __restrict__ Bw,
    const float* __restrict__ bias, ushort_t* __restrict__ o16a,
    ushort_t* __restrict__ o16b, float* __restrict__ o32,
    int M, int N, int K) {
  __shared__ __align__(16) ushort_t As[128 * 32];
  __shared__ __align__(16) ushort_t Bs[128 * 32];
  const int tid = threadIdx.x;
  const int wave = tid >> 6, lane = tid & 63;
  const int wm = wave >> 1, wn = wave & 1;
  const int bm = blockIdx.y * 128, bn = blockIdx.x * 128;
  const int fr = lane & 15, fq = lane >> 4;

  // staging: thread t covers tile row t/4 (64 rows/round, 2 rounds), col 8*(t%4)
  const int rT = tid >> 2;
  const int cT = (tid & 3) << 3;
  const ushort_t* ag = A + (size_t)(bm + rT) * K + cT;
  const ushort_t* bg = Bw + (size_t)(bn + rT) * K + cT;
  char* al = (char*)As + (wave << 10);
  char* bl = (char*)Bs + (wave << 10);

  floatx4 acc[4][4] = {};

  for (int k0 = 0; k0 < K; k0 += 32) {
    __syncthreads();  // previous iter's LDS reads done
    gld16(ag + k0, al);
    gld16(ag + k0 + (size_t)64 * K, al + 4096);
    gld16(bg + k0, bl);
    gld16(bg + k0 + (size_t)64 * K, bl + 4096);
    __syncthreads();  // drains vmcnt (compiler emits vmcnt(0) before s_barrier)
    bf16x8 af[4], bf[4];
#pragma unroll
    for (int i = 0; i < 4; i++)
      af[i] = *(const bf16x8*)(As + (wm * 64 + i * 16 + fr) * 32 + fq * 8);
#pragma unroll
    for (int j = 0; j < 4; j++)
      bf[j] = *(const bf16x8*)(Bs + (wn * 64 + j * 16 + fr) * 32 + fq * 8);
#pragma unroll
    for (int i = 0; i < 4; i++)
#pragma unroll
      for (int j = 0; j < 4; j++)
        acc[i][j] = mfma16(af[i], bf[j], acc[i][j]);
  }

#pragma unroll
  for (int i = 0; i < 4; i++) {
#pragma unroll
    for (int j = 0; j < 4; j++) {
#pragma unroll
      for (int r = 0; r < 4; r++) {
        int m = bm + wm * 64 + i * 16 + fq * 4 + r;   // C row
        int n = bn + wn * 64 + j * 16 + fr;           // C col
        float v = acc[i][j][r] + bias[n];
        if (MODE == 0) {
          int b = m >> 11, s = m & 2047, h = n >> 6, d = n & 63;
          o16a[(((size_t)b * NHEADS + h) * S_LEN + s) * DHEAD + d] = f2bf(v);
        } else if (MODE == 1) {
          int b = m >> 11, s = m & 2047, h = n >> 7, jj = n & 127;
          if (jj < 64)
            o16a[(((size_t)b * NHEADS + h) * S_LEN + s) * DHEAD + jj] = f2bf(v);
          else
            o16b[(((size_t)b * NHEADS + h) * DHEAD + (jj - 64)) * S_LEN + s] = f2bf(v);
        } else {
          o32[(size_t)m * DMODEL + n] = v;
        }
      }
    }
  }
}

// Flash attention: one block per (q-tile of 64, b*h). 4 waves; wave w owns q rows
// [w*16, w*16+16). Online softmax per row; P goes C-layout -> LDS -> A-layout.
__global__ __launch_bounds__(256, 2) void flash_attn(
    const ushort_t* __restrict__ Qh, const ushort_t* __restrict__ Kh,
    const ushort_t* __restrict__ Vt, const float* __restrict__ mask,
    const int* __restrict__ mask_is_zero, ushort_t* __restrict__ Oh) {
  __shared__ __align__(16) ushort_t Qs[64 * 64];
  __shared__ __align__(16) ushort_t Ks[64 * 64];
  __shared__ __align__(16) ushort_t Vs[64 * 64];       // V^T tile: [d][s_local]
  __shared__ __align__(16) ushort_t Ps[4][16 * 64];    // per-wave P
  const int qt = blockIdx.x, bh = blockIdx.y;
  const int b = bh / NHEADS, h = bh % NHEADS;
  const int tid = threadIdx.x, wave = tid >> 6, lane = tid & 63;
  const int li = lane & 15, lg = lane >> 4;
  const bool use_mask = (*mask_is_zero == 0);

  // stage Q tile (contiguous 8KB in global)
  const ushort_t* qg = Qh + ((size_t)bh * S_LEN + qt * 64) * DHEAD;
  gld16(qg + tid * 8, (char*)Qs + (wave << 10));
  gld16(qg + 2048 + tid * 8, (char*)Qs + 4096 + (wave << 10));
  __syncthreads();
  bf16x8 qf[2];  // loop-invariant A-fragments: Q[m=wave*16+li][kk*32 + lg*8 + j]
  qf[0] = *(const bf16x8*)(Qs + (wave * 16 + li) * 64 + lg * 8);
  qf[1] = *(const bf16x8*)(Qs + (wave * 16 + li) * 64 + 32 + lg * 8);

  float m_i[4], l_i[4];
  floatx4 o_acc[4] = {};
#pragma unroll
  for (int r = 0; r < 4; r++) { m_i[r] = -1e30f; l_i[r] = 0.f; }

  const ushort_t* kgbase = Kh + (size_t)bh * S_LEN * DHEAD;
  const ushort_t* vgbase = Vt + (size_t)bh * DHEAD * S_LEN;
  const int vrow = tid >> 3;        // 0..31 (V^T tile row per round)
  const int vcol = (tid & 7) << 3;  // 0..56

  for (int kt = 0; kt < S_LEN / 64; kt++) {
    __syncthreads();
    const ushort_t* kg = kgbase + (size_t)kt * 64 * DHEAD;
    gld16(kg + tid * 8, (char*)Ks + (wave << 10));
    gld16(kg + 2048 + tid * 8, (char*)Ks + 4096 + (wave << 10));
    gld16(vgbase + (size_t)vrow * S_LEN + kt * 64 + vcol, (char*)Vs + (wave << 10));
    gld16(vgbase + (size_t)(vrow + 32) * S_LEN + kt * 64 + vcol,
          (char*)Vs + 4096 + (wave << 10));
    __syncthreads();

    // S = Q @ K^T : 4 col-tiles of 16 keys
    floatx4 sc[4];
#pragma unroll
    for (int c = 0; c < 4; c++) {
      floatx4 s = {};
      bf16x8 kf0 = *(const bf16x8*)(Ks + (c * 16 + li) * 64 + lg * 8);
      bf16x8 kf1 = *(const bf16x8*)(Ks + (c * 16 + li) * 64 + 32 + lg * 8);
      s = mfma16(qf[0], kf0, s);
      s = mfma16(qf[1], kf1, s);
      sc[c] = s;
    }
    // scale + optional mask; C-layout: row = lg*4+r, col = c*16+li
    float p[4][4];
#pragma unroll
    for (int c = 0; c < 4; c++)
#pragma unroll
      for (int r = 0; r < 4; r++) p[c][r] = sc[c][r] * 0.125f;
    if (use_mask) {
      const float* mrow = mask + (size_t)(qt * 64 + wave * 16 + lg * 4) * S_LEN + kt * 64;
#pragma unroll
      for (int r = 0; r < 4; r++)
#pragma unroll
        for (int c = 0; c < 4; c++)
          p[c][r] += mrow[(size_t)r * S_LEN + c * 16 + li];
    }
    // online softmax: each 16-lane group owns rows lg*4..lg*4+3
    float alpha[4];
#pragma unroll
    for (int r = 0; r < 4; r++) {
      float t = fmaxf(fmaxf(p[0][r], p[1][r]), fmaxf(p[2][r], p[3][r]));
#pragma unroll
      for (int d = 1; d < 16; d <<= 1) t = fmaxf(t, __shfl_xor(t, d));
      float mnew = fmaxf(m_i[r], t);
      alpha[r] = __expf(m_i[r] - mnew);
      m_i[r] = mnew;
      float srow = 0.f;
#pragma unroll
      for (int c = 0; c < 4; c++) {
        p[c][r] = __expf(p[c][r] - mnew);
        srow += p[c][r];
      }
#pragma unroll
      for (int d = 1; d < 16; d <<= 1) srow += __shfl_xor(srow, d);
      l_i[r] = l_i[r] * alpha[r] + srow;
    }
#pragma unroll
    for (int dt = 0; dt < 4; dt++)
#pragma unroll
      for (int r = 0; r < 4; r++) o_acc[dt][r] *= alpha[r];

    // P: C-layout -> LDS (per-wave buffer; same-wave dep, no barrier needed)
    ushort_t* pw = Ps[wave];
#pragma unroll
    for (int c = 0; c < 4; c++)
#pragma unroll
      for (int r = 0; r < 4; r++)
        pw[(lg * 4 + r) * 64 + c * 16 + li] = f2bf(p[c][r]);

    // O += P @ V : A-frag P[m=li][k], B-frag V^T[n=d][k=s_local]
#pragma unroll
    for (int kk = 0; kk < 2; kk++) {
      bf16x8 pf = *(const bf16x8*)(pw + li * 64 + kk * 32 + lg * 8);
#pragma unroll
      for (int dt = 0; dt < 4; dt++) {
        bf16x8 vf = *(const bf16x8*)(Vs + (dt * 16 + li) * 64 + kk * 32 + lg * 8);
        o_acc[dt] = mfma16(pf, vf, o_acc[dt]);
      }
    }
  }

  // epilogue: write O/l in (B,S,H*Dh) bf16 layout for the out-proj GEMM
#pragma unroll
  for (int r = 0; r < 4; r++) {
    float inv = 1.0f / l_i[r];
    int qrow = qt * 64 + wave * 16 + lg * 4 + r;
#pragma unroll
    for (int dt = 0; dt < 4; dt++) {
      int d = dt * 16 + li;
      Oh[((size_t)b * S_LEN + qrow) * DMODEL + h * DHEAD + d] = f2bf(o_acc[dt][r] * inv);
    }
  }
}

extern "C" void kernel_launch(void* const* d_in, const int* in_sizes, int n_in,
                              void* d_out, int out_size, void* d_ws, size_t ws_size,
                              hipStream_t stream) {
  const float* x = (const float*)d_in[0];
  const float* y = (const float*)d_in[1];
  const float* mask = (const float*)d_in[2];
  const float* Wq = (const float*)d_in[3];
  const float* bq = (const float*)d_in[4];
  const float* Wkv = (const float*)d_in[5];
  const float* bkv = (const float*)d_in[6];
  const float* Wo = (const float*)d_in[7];
  const float* bo = (const float*)d_in[8];
  float* out = (float*)d_out;

  ushort_t* ws = (ushort_t*)d_ws;
  const size_t XN = (size_t)BATCH * S_LEN * DMODEL;  // 6,291,456
  ushort_t* xb = ws;
  ushort_t* yb = xb + XN;
  ushort_t* wqb = yb + XN;
  ushort_t* wkvb = wqb + (size_t)DMODEL * DMODEL;
  ushort_t* wob = wkvb + (size_t)2 * DMODEL * DMODEL;
  ushort_t* Qh = wob + (size_t)DMODEL * DMODEL;
  ushort_t* Kh = Qh + XN;
  ushort_t* Vt = Kh + XN;
  int* flag = (int*)(Vt + XN);
  ushort_t* Oh = xb;  // alias: xb dead after Q-projection

  init_flag<<<1, 1, 0, stream>>>(flag);
  mask_check<<<(S_LEN * S_LEN / 4) / 256, 256, 0, stream>>>(mask, flag);
  cvt_bf16<<<6144, 256, 0, stream>>>(x, xb, (int)(XN / 4));
  cvt_bf16<<<6144, 256, 0, stream>>>(y, yb, (int)(XN / 4));
  cvt_bf16<<<576, 256, 0, stream>>>(Wq, wqb, DMODEL * DMODEL / 4);
  cvt_bf16<<<1152, 256, 0, stream>>>(Wkv, wkvb, 2 * DMODEL * DMODEL / 4);
  cvt_bf16<<<576, 256, 0, stream>>>(Wo, wob, DMODEL * DMODEL / 4);
  gemm_bt<0><<<dim3(6, 64), 256, 0, stream>>>(xb, wqb, bq, Qh, nullptr, nullptr,
                                              BATCH * S_LEN, DMODEL, DMODEL);
  gemm_bt<1><<<dim3(12, 64), 256, 0, stream>>>(yb, wkvb, bkv, Kh, Vt, nullptr,
                                               BATCH * S_LEN, 2 * DMODEL, DMODEL);
  flash_attn<<<dim3(S_LEN / 64, BATCH * NHEADS), 256, 0, stream>>>(Qh, Kh, Vt, mask, flag, Oh);
  gemm_bt<2><<<dim3(6, 64), 256, 0, stream>>>(Oh, wob, bo, nullptr, nullptr, out,
                                              BATCH * S_LEN, DMODEL, DMODEL);
}

// Round 2
// 326.522 us; speedup vs baseline: 1.3015x; 1.3015x over previous
//
#include <hip/hip_runtime.h>
#include <cstdint>

#define S_LEN 2048
#define BATCH 4
#define NHEADS 12
#define DHEAD 64
#define DMODEL 768
#define SCALE_LOG2E 0.18033688011112042f  // (1/sqrt(64)) * log2(e)
#define LOG2E 1.4426950408889634f

typedef unsigned short ushort_t;
typedef __attribute__((ext_vector_type(8))) __bf16 bf16x8;
typedef __attribute__((ext_vector_type(4))) float floatx4;

// fp32 -> bf16 round-to-nearest-even (finite values only)
__device__ __forceinline__ ushort_t f2bf(float f) {
  unsigned int u = __builtin_bit_cast(unsigned int, f);
  u += 0x7fffu + ((u >> 16) & 1u);
  return (ushort_t)(u >> 16);
}

__device__ __forceinline__ float fexp2(float x) {
#if __has_builtin(__builtin_amdgcn_exp2f)
  return __builtin_amdgcn_exp2f(x);
#else
  return exp2f(x);
#endif
}

// async global->LDS, 16B/lane. LDS dest is wave-uniform base; HW adds lane*16.
__device__ __forceinline__ void gld16(const void* g, void* s) {
  __builtin_amdgcn_global_load_lds(
      (const __attribute__((address_space(1))) void*)g,
      (__attribute__((address_space(3))) void*)s, 16, 0, 0);
}

__device__ __forceinline__ floatx4 mfma16(bf16x8 a, bf16x8 b, floatx4 c) {
  return __builtin_amdgcn_mfma_f32_16x16x32_bf16(a, b, c, 0, 0, 0);
}

__global__ void init_flag(int* flag) { *flag = 1; }

__global__ void mask_check(const float* __restrict__ mask, int* __restrict__ flag) {
  int i = blockIdx.x * 256 + threadIdx.x;  // grid sized exactly: S*S/4 threads
  float4 v = ((const float4*)mask)[i];
  if (v.x != 0.f || v.y != 0.f || v.z != 0.f || v.w != 0.f) *flag = 0;
}

// single kernel converting all 5 fp32 tensors to bf16 (one launch)
__global__ void cvt_all(const float* __restrict__ x, ushort_t* __restrict__ xb,
                        const float* __restrict__ y, ushort_t* __restrict__ yb,
                        const float* __restrict__ wq, ushort_t* __restrict__ wqb,
                        const float* __restrict__ wkv, ushort_t* __restrict__ wkvb,
                        const float* __restrict__ wo, ushort_t* __restrict__ wob) {
  int bx = blockIdx.x;
  const float* s;
  ushort_t* d;
  int base;
  if (bx < 6144) { s = x; d = xb; base = bx; }
  else if (bx < 12288) { s = y; d = yb; base = bx - 6144; }
  else if (bx < 12864) { s = wq; d = wqb; base = bx - 12288; }
  else if (bx < 14016) { s = wkv; d = wkvb; base = bx - 12864; }
  else { s = wo; d = wob; base = bx - 14016; }
  int i = base * 256 + threadIdx.x;
  float4 v = ((const float4*)s)[i];
  ushort4 o;
  o.x = f2bf(v.x); o.y = f2bf(v.y); o.z = f2bf(v.z); o.w = f2bf(v.w);
  ((ushort4*)d)[i] = o;
}

// C[M,N] = A[M,K] @ B[N,K]^T + bias[n], bf16 in, fp32 acc. 128x128 tile, BK=32.
// XOR-swizzled LDS (chunk ^ (row&3)) via DMA source permutation -> 2-way max.
// MODE 0: scatter Q->(B,H,S,Dh) bf16 scaled by SCALE_LOG2E.
// MODE 1: split KV -> K(B,H,S,Dh), V^T(B,H,Dh,S) bf16.  MODE 2: fp32 [M,N].
template <int MODE>
__global__ __launch_bounds__(256, 2) void gemm_bt(
    const ushort_t* __restrict__ A, const ushort_t* __restrict__ Bw,
    const float* __restrict__ bias, ushort_t* __restrict__ o16a,
    ushort_t* __restrict__ o16b, float* __restrict__ o32,
    int M, int N, int K) {
  __shared__ __align__(16) ushort_t As[128 * 32];
  __shared__ __align__(16) ushort_t Bs[128 * 32];
  const int tid = threadIdx.x;
  const int wave = tid >> 6, lane = tid & 63;
  const int wm = wave >> 1, wn = wave & 1;
  const int bm = blockIdx.y * 128, bn = blockIdx.x * 128;
  const int fr = lane & 15, fq = lane >> 4;

  // staging: thread t covers tile row t/4, swizzled chunk (t&3)^((t>>2)&3)
  const int rT = tid >> 2;
  const int cT = ((tid & 3) ^ (rT & 3)) << 3;
  const ushort_t* ag = A + (size_t)(bm + rT) * K + cT;
  const ushort_t* bg = Bw + (size_t)(bn + rT) * K + cT;
  char* al = (char*)As + (wave << 10);
  char* bl = (char*)Bs + (wave << 10);

  floatx4 acc[4][4] = {};

  for (int k0 = 0; k0 < K; k0 += 32) {
    __syncthreads();
    gld16(ag + k0, al);
    gld16(ag + k0 + (size_t)64 * K, al + 4096);
    gld16(bg + k0, bl);
    gld16(bg + k0 + (size_t)64 * K, bl + 4096);
    __syncthreads();
    bf16x8 af[4], bf[4];
#pragma unroll
    for (int i = 0; i < 4; i++)
      af[i] = *(const bf16x8*)(As + (wm * 64 + i * 16 + fr) * 32 + ((fq ^ (fr & 3)) << 3));
#pragma unroll
    for (int j = 0; j < 4; j++)
      bf[j] = *(const bf16x8*)(Bs + (wn * 64 + j * 16 + fr) * 32 + ((fq ^ (fr & 3)) << 3));
#pragma unroll
    for (int i = 0; i < 4; i++)
#pragma unroll
      for (int j = 0; j < 4; j++)
        acc[i][j] = mfma16(af[i], bf[j], acc[i][j]);
  }

#pragma unroll
  for (int i = 0; i < 4; i++) {
#pragma unroll
    for (int j = 0; j < 4; j++) {
#pragma unroll
      for (int r = 0; r < 4; r++) {
        int m = bm + wm * 64 + i * 16 + fq * 4 + r;   // C row
        int n = bn + wn * 64 + j * 16 + fr;           // C col
        float v = acc[i][j][r] + bias[n];
        if (MODE == 0) {
          int b = m >> 11, s = m & 2047, h = n >> 6, d = n & 63;
          o16a[(((size_t)b * NHEADS + h) * S_LEN + s) * DHEAD + d] = f2bf(v * SCALE_LOG2E);
        } else if (MODE == 1) {
          int b = m >> 11, s = m & 2047, h = n >> 7, jj = n & 127;
          if (jj < 64)
            o16a[(((size_t)b * NHEADS + h) * S_LEN + s) * DHEAD + jj] = f2bf(v);
          else
            o16b[(((size_t)b * NHEADS + h) * DHEAD + (jj - 64)) * S_LEN + s] = f2bf(v);
        } else {
          o32[(size_t)m * DMODEL + n] = v;
        }
      }
    }
  }
}

// Flash attention. Block = 128 q-rows x (b,h); wave w owns q-rows [w*32,w*32+32).
// Q frags direct global->VGPR (loop-invariant). K/V double-buffered in LDS with
// XOR swizzle (chunk16 ^ (row&7)) realized through DMA source permutation ->
// conflict-free ds_read_b128. Scores in exp2 domain (scale folded into Q).
__global__ __launch_bounds__(256, 3) void flash_attn(
    const ushort_t* __restrict__ Qh, const ushort_t* __restrict__ Kh,
    const ushort_t* __restrict__ Vt, const float* __restrict__ mask,
    const int* __restrict__ mask_is_zero, ushort_t* __restrict__ Oh) {
  __shared__ __align__(16) ushort_t Ks[2][64 * 64];
  __shared__ __align__(16) ushort_t Vs[2][64 * 64];   // V^T tile [d][s_local]
  __shared__ __align__(16) ushort_t Ps[4][32 * 64];   // per-wave P, swizzled
  const int qt = blockIdx.x, bh = blockIdx.y;
  const int b = bh / NHEADS, h = bh % NHEADS;
  const int tid = threadIdx.x, w = tid >> 6, lane = tid & 63;
  const int li = lane & 15, lg = lane >> 4, sx = li & 7;
  const int phi = li >> 3, plo = li & 7;
  const bool use_mask = (*mask_is_zero == 0);

  // Q fragments: lane holds Q[m*16+li][kk*32+lg*8 ..+8]
  const int q0 = qt * 128 + w * 32;
  const ushort_t* qg = Qh + ((size_t)bh * S_LEN + q0) * DHEAD;
  bf16x8 qf[2][2];
#pragma unroll
  for (int m = 0; m < 2; m++)
#pragma unroll
    for (int kk = 0; kk < 2; kk++)
      qf[m][kk] = *(const bf16x8*)(qg + (m * 16 + li) * 64 + kk * 32 + lg * 8);

  // staging geometry: lane i covers tile row w*16 + (i>>3) (+8), chunk (i&7)^(i>>3)
  const int srow = lane >> 3;
  const int schk = (lane & 7) ^ srow;
  const ushort_t* kg = Kh + (size_t)bh * S_LEN * DHEAD;
  const ushort_t* vg = Vt + (size_t)bh * DHEAD * S_LEN;

  float m_i[2][4], l_p[2][4];
  floatx4 o_acc[2][4] = {};
#pragma unroll
  for (int m = 0; m < 2; m++)
#pragma unroll
    for (int r = 0; r < 4; r++) { m_i[m][r] = -1e30f; l_p[m][r] = 0.f; }

#define STAGE(KT, BUF)                                                          \
  {                                                                             \
    const ushort_t* k0_ = kg + (size_t)((KT)*64 + w * 16 + srow) * 64 + schk * 8; \
    gld16(k0_, (char*)Ks + (BUF)*8192 + w * 2048);                              \
    gld16(k0_ + 8 * 64, (char*)Ks + (BUF)*8192 + w * 2048 + 1024);              \
    const ushort_t* v0_ = vg + (size_t)(w * 16 + srow) * 2048 + (KT)*64 + schk * 8; \
    gld16(v0_, (char*)Vs + (BUF)*8192 + w * 2048);                              \
    gld16(v0_ + 8 * 2048, (char*)Vs + (BUF)*8192 + w * 2048 + 1024);            \
  }

  STAGE(0, 0);
  __syncthreads();

  for (int kt = 0; kt < S_LEN / 64; kt++) {
    const int cur = kt & 1;
    if (kt < S_LEN / 64 - 1) STAGE(kt + 1, cur ^ 1);
    const ushort_t* Kc = Ks[cur];
    const ushort_t* Vc = Vs[cur];

    // S' = (Q*scale*log2e) @ K^T   (scores already in exp2 domain)
    floatx4 sc[2][4];
#pragma unroll
    for (int c = 0; c < 4; c++) {
      bf16x8 kf0 = *(const bf16x8*)(Kc + (c * 16 + li) * 64 + ((lg ^ sx) << 3));
      bf16x8 kf1 = *(const bf16x8*)(Kc + (c * 16 + li) * 64 + (((4 + lg) ^ sx) << 3));
#pragma unroll
      for (int m = 0; m < 2; m++) {
        floatx4 s = {};
        s = mfma16(qf[m][0], kf0, s);
        s = mfma16(qf[m][1], kf1, s);
        sc[m][c] = s;
      }
    }
    if (use_mask) {
#pragma unroll
      for (int m = 0; m < 2; m++)
#pragma unroll
        for (int r = 0; r < 4; r++) {
          const float* mrow =
              mask + (size_t)(q0 + m * 16 + lg * 4 + r) * S_LEN + kt * 64;
#pragma unroll
          for (int c = 0; c < 4; c++) sc[m][c][r] += mrow[c * 16 + li] * LOG2E;
        }
    }

    // online softmax (exp2 domain); row rho = m*16+lg*4+r lives in 16-lane group
    float alpha[2][4];
#pragma unroll
    for (int m = 0; m < 2; m++) {
#pragma unroll
      for (int r = 0; r < 4; r++) {
        float t = fmaxf(fmaxf(sc[m][0][r], sc[m][1][r]),
                        fmaxf(sc[m][2][r], sc[m][3][r]));
#pragma unroll
        for (int d = 1; d < 16; d <<= 1) t = fmaxf(t, __shfl_xor(t, d));
        float mn = fmaxf(m_i[m][r], t);
        alpha[m][r] = fexp2(m_i[m][r] - mn);
        m_i[m][r] = mn;
        float s0 = fexp2(sc[m][0][r] - mn);
        float s1 = fexp2(sc[m][1][r] - mn);
        float s2 = fexp2(sc[m][2][r] - mn);
        float s3 = fexp2(sc[m][3][r] - mn);
        sc[m][0][r] = s0; sc[m][1][r] = s1; sc[m][2][r] = s2; sc[m][3][r] = s3;
        l_p[m][r] = l_p[m][r] * alpha[m][r] + (s0 + s1) + (s2 + s3);  // lane-partial
      }
#pragma unroll
      for (int dt = 0; dt < 4; dt++)
#pragma unroll
        for (int r = 0; r < 4; r++) o_acc[m][dt][r] *= alpha[m][r];
    }

    // P (C-layout) -> per-wave swizzled LDS
    ushort_t* pw = Ps[w];
#pragma unroll
    for (int m = 0; m < 2; m++) {
#pragma unroll
      for (int r = 0; r < 4; r++) {
        int rho = m * 16 + lg * 4 + r;
#pragma unroll
        for (int c = 0; c < 4; c++)
          pw[rho * 64 + (((c * 2 + phi) ^ (rho & 7)) << 3) + plo] = f2bf(sc[m][c][r]);
      }
    }

    // O += P @ V
#pragma unroll
    for (int kk = 0; kk < 2; kk++) {
      bf16x8 pf[2];
#pragma unroll
      for (int m = 0; m < 2; m++)
        pf[m] = *(const bf16x8*)(pw + (m * 16 + li) * 64 + (((kk * 4 + lg) ^ sx) << 3));
#pragma unroll
      for (int dt = 0; dt < 4; dt++) {
        bf16x8 vf = *(const bf16x8*)(Vc + (dt * 16 + li) * 64 + (((kk * 4 + lg) ^ sx) << 3));
#pragma unroll
        for (int m = 0; m < 2; m++) o_acc[m][dt] = mfma16(pf[m], vf, o_acc[m][dt]);
      }
    }
    __syncthreads();  // reads of cur done; prefetch DMA drained (vmcnt before barrier)
  }

  // epilogue: reduce lane-partial l over the 16-lane row group, write O
#pragma unroll
  for (int m = 0; m < 2; m++) {
#pragma unroll
    for (int r = 0; r < 4; r++) {
      float l = l_p[m][r];
#pragma unroll
      for (int d = 1; d < 16; d <<= 1) l += __shfl_xor(l, d);
      float inv = 1.0f / l;
      int row = q0 + m * 16 + lg * 4 + r;
      ushort_t* ob = Oh + ((size_t)b * S_LEN + row) * DMODEL + h * DHEAD;
#pragma unroll
      for (int dt = 0; dt < 4; dt++) ob[dt * 16 + li] = f2bf(o_acc[m][dt][r] * inv);
    }
  }
}

extern "C" void kernel_launch(void* const* d_in, const int* in_sizes, int n_in,
                              void* d_out, int out_size, void* d_ws, size_t ws_size,
                              hipStream_t stream) {
  const float* x = (const float*)d_in[0];
  const float* y = (const float*)d_in[1];
  const float* mask = (const float*)d_in[2];
  const float* Wq = (const float*)d_in[3];
  const float* bq = (const float*)d_in[4];
  const float* Wkv = (const float*)d_in[5];
  const float* bkv = (const float*)d_in[6];
  const float* Wo = (const float*)d_in[7];
  const float* bo = (const float*)d_in[8];
  float* out = (float*)d_out;

  ushort_t* ws = (ushort_t*)d_ws;
  const size_t XN = (size_t)BATCH * S_LEN * DMODEL;  // 6,291,456
  ushort_t* xb = ws;
  ushort_t* yb = xb + XN;
  ushort_t* wqb = yb + XN;
  ushort_t* wkvb = wqb + (size_t)DMODEL * DMODEL;
  ushort_t* wob = wkvb + (size_t)2 * DMODEL * DMODEL;
  ushort_t* Qh = wob + (size_t)DMODEL * DMODEL;
  ushort_t* Kh = Qh + XN;
  ushort_t* Vt = Kh + XN;
  int* flag = (int*)(Vt + XN);
  ushort_t* Oh = xb;  // alias: xb dead after Q-projection

  init_flag<<<1, 1, 0, stream>>>(flag);
  mask_check<<<(S_LEN * S_LEN / 4) / 256, 256, 0, stream>>>(mask, flag);
  cvt_all<<<14592, 256, 0, stream>>>(x, xb, y, yb, Wq, wqb, Wkv, wkvb, Wo, wob);
  gemm_bt<0><<<dim3(6, 64), 256, 0, stream>>>(xb, wqb, bq, Qh, nullptr, nullptr,
                                              BATCH * S_LEN, DMODEL, DMODEL);
  gemm_bt<1><<<dim3(12, 64), 256, 0, stream>>>(yb, wkvb, bkv, Kh, Vt, nullptr,
                                               BATCH * S_LEN, 2 * DMODEL, DMODEL);
  flash_attn<<<dim3(S_LEN / 128, BATCH * NHEADS), 256, 0, stream>>>(Qh, Kh, Vt, mask,
                                                                    flag, Oh);
  gemm_bt<2><<<dim3(6, 64), 256, 0, stream>>>(Oh, wob, bo, nullptr, nullptr, out,
                                              BATCH * S_LEN, DMODEL, DMODEL);
}

// Round 3
// 284.119 us; speedup vs baseline: 1.4958x; 1.1492x over previous
//
#include <hip/hip_runtime.h>
#include <cstdint>

#define S_LEN 2048
#define BATCH 4
#define NHEADS 12
#define DHEAD 64
#define DMODEL 768
#define SCALE_LOG2E 0.18033688011112042f  // (1/sqrt(64)) * log2(e)
#define LOG2E 1.4426950408889634f

typedef unsigned short ushort_t;
typedef __attribute__((ext_vector_type(8))) __bf16 bf16x8;
typedef __attribute__((ext_vector_type(4))) float floatx4;

// fp32 -> bf16 round-to-nearest-even (finite values only)
__device__ __forceinline__ ushort_t f2bf(float f) {
  unsigned u = __builtin_bit_cast(unsigned, f);
  u += 0x7fffu + ((u >> 16) & 1u);
  return (ushort_t)(u >> 16);
}

// pack two fp32 -> two bf16 (RTNE): a -> low16, b -> high16. v_perm_b32:
// sel bytes 0-3 pick from S1 (=ua), 4-7 from S0 (=ub); 0x07060302 = {ua.b2,ua.b3,ub.b2,ub.b3}
__device__ __forceinline__ unsigned pk2bf(float a, float b) {
  unsigned ua = __builtin_bit_cast(unsigned, a);
  unsigned ub = __builtin_bit_cast(unsigned, b);
  ua += 0x7fffu + ((ua >> 16) & 1u);
  ub += 0x7fffu + ((ub >> 16) & 1u);
  return __builtin_amdgcn_perm(ub, ua, 0x07060302);
}

__device__ __forceinline__ float fexp2(float x) {
#if __has_builtin(__builtin_amdgcn_exp2f)
  return __builtin_amdgcn_exp2f(x);
#else
  return exp2f(x);
#endif
}

// async global->LDS, 16B/lane. LDS dest is wave-uniform base; HW adds lane*16.
__device__ __forceinline__ void gld16(const void* g, void* s) {
  __builtin_amdgcn_global_load_lds(
      (const __attribute__((address_space(1))) void*)g,
      (__attribute__((address_space(3))) void*)s, 16, 0, 0);
}

__device__ __forceinline__ floatx4 mfma16(bf16x8 a, bf16x8 b, floatx4 c) {
  return __builtin_amdgcn_mfma_f32_16x16x32_bf16(a, b, c, 0, 0, 0);
}

__global__ void init_flag(int* flag) { *flag = 1; }

// fused: bf16 conversion of all 5 fp32 tensors + mask-zero check (one launch)
__global__ void cvt_mask(const float* __restrict__ x, ushort_t* __restrict__ xb,
                         const float* __restrict__ y, ushort_t* __restrict__ yb,
                         const float* __restrict__ wq, ushort_t* __restrict__ wqb,
                         const float* __restrict__ wkv, ushort_t* __restrict__ wkvb,
                         const float* __restrict__ wo, ushort_t* __restrict__ wob,
                         const float* __restrict__ mask, int* __restrict__ flag) {
  int bx = blockIdx.x;
  if (bx >= 14592) {  // 4096 mask-check blocks (S*S/4 floats)
    int i = (bx - 14592) * 256 + threadIdx.x;
    float4 v = ((const float4*)mask)[i];
    if (v.x != 0.f || v.y != 0.f || v.z != 0.f || v.w != 0.f) *flag = 0;
    return;
  }
  const float* s;
  ushort_t* d;
  int base;
  if (bx < 6144) { s = x; d = xb; base = bx; }
  else if (bx < 12288) { s = y; d = yb; base = bx - 6144; }
  else if (bx < 12864) { s = wq; d = wqb; base = bx - 12288; }
  else if (bx < 14016) { s = wkv; d = wkvb; base = bx - 12864; }
  else { s = wo; d = wob; base = bx - 14016; }
  int i = base * 256 + threadIdx.x;
  float4 v = ((const float4*)s)[i];
  uint2 o;
  o.x = pk2bf(v.x, v.y);
  o.y = pk2bf(v.z, v.w);
  ((uint2*)d)[i] = o;
}

#define GSTAGE(K0, BUF)                                                   \
  {                                                                       \
    gld16(ag + (K0), (char*)As + (BUF)*8192 + (wave << 10));              \
    gld16(ag + (K0) + 64 * K, (char*)As + (BUF)*8192 + (wave << 10) + 4096); \
    gld16(bg + (K0), (char*)Bs + (BUF)*8192 + (wave << 10));              \
    gld16(bg + (K0) + 64 * K, (char*)Bs + (BUF)*8192 + (wave << 10) + 4096); \
  }

// Fused Q + KV projection. grid (18, 64): bx<6 -> Q tile, else KV tile.
// Double-buffered LDS (single barrier/iter), XOR-swizzled staging.
// Q out: (B,H,S,Dh) bf16, scaled by SCALE_LOG2E (softmax scale folded).
// KV out: K (B,H,S,Dh) bf16; V^T (B,H,Dh,S) bf16 with per-64 sigma-permuted
// s-positions (position p holds key (p&3)*16+(p>>2)) for packed P writes in flash.
__global__ __launch_bounds__(256, 3) void gemm_qkv(
    const ushort_t* __restrict__ xb, const ushort_t* __restrict__ wqb,
    const float* __restrict__ bq, ushort_t* __restrict__ Qh,
    const ushort_t* __restrict__ yb, const ushort_t* __restrict__ wkvb,
    const float* __restrict__ bkv, ushort_t* __restrict__ Kh,
    ushort_t* __restrict__ Vt) {
  __shared__ __align__(16) ushort_t As[2][128 * 32];
  __shared__ __align__(16) ushort_t Bs[2][128 * 32];
  const int tid = threadIdx.x;
  const int wave = tid >> 6, lane = tid & 63;
  const int wm = wave >> 1, wn = wave & 1;
  const bool isQ = blockIdx.x < 6;
  const int bn = (isQ ? blockIdx.x : blockIdx.x - 6) * 128;
  const int bm = blockIdx.y * 128;
  const ushort_t* A = isQ ? xb : yb;
  const ushort_t* W = isQ ? wqb : wkvb;
  const float* bias = isQ ? bq : bkv;
  const int K = DMODEL;
  const int fr = lane & 15, fq = lane >> 4;

  const int rT = tid >> 2;
  const int cT = ((tid & 3) ^ (rT & 3)) << 3;
  const ushort_t* ag = A + (size_t)(bm + rT) * K + cT;
  const ushort_t* bg = W + (size_t)(bn + rT) * K + cT;

  floatx4 acc[4][4] = {};
  GSTAGE(0, 0);
  __syncthreads();
  for (int k0 = 0; k0 < K; k0 += 32) {
    const int cur = (k0 >> 5) & 1;
    if (k0 + 32 < K) GSTAGE(k0 + 32, cur ^ 1);
    const ushort_t* Ac = As[cur];
    const ushort_t* Bc = Bs[cur];
    bf16x8 af[4], bf[4];
#pragma unroll
    for (int i = 0; i < 4; i++)
      af[i] = *(const bf16x8*)(Ac + (wm * 64 + i * 16 + fr) * 32 + ((fq ^ (fr & 3)) << 3));
#pragma unroll
    for (int j = 0; j < 4; j++)
      bf[j] = *(const bf16x8*)(Bc + (wn * 64 + j * 16 + fr) * 32 + ((fq ^ (fr & 3)) << 3));
#pragma unroll
    for (int i = 0; i < 4; i++)
#pragma unroll
      for (int j = 0; j < 4; j++)
        acc[i][j] = mfma16(af[i], bf[j], acc[i][j]);
    __syncthreads();
  }

#pragma unroll
  for (int i = 0; i < 4; i++) {
#pragma unroll
    for (int j = 0; j < 4; j++) {
#pragma unroll
      for (int r = 0; r < 4; r++) {
        int m = bm + wm * 64 + i * 16 + fq * 4 + r;
        int n = bn + wn * 64 + j * 16 + fr;
        float v = acc[i][j][r] + bias[n];
        int b = m >> 11, s = m & 2047;
        if (isQ) {
          int h = n >> 6, d = n & 63;
          Qh[(((size_t)b * NHEADS + h) * S_LEN + s) * DHEAD + d] = f2bf(v * SCALE_LOG2E);
        } else {
          int h = n >> 7, jj = n & 127;
          if (jj < 64) {
            Kh[(((size_t)b * NHEADS + h) * S_LEN + s) * DHEAD + jj] = f2bf(v);
          } else {
            int sp = (s & ~63) | ((s & 15) << 2) | ((s >> 4) & 3);  // sigma-permute
            Vt[(((size_t)b * NHEADS + h) * DHEAD + (jj - 64)) * S_LEN + sp] = f2bf(v);
          }
        }
      }
    }
  }
}

// Output projection: C[M,768] fp32 = Oh @ Wo^T + bo. Same dbuf structure.
__global__ __launch_bounds__(256, 3) void gemm_out(
    const ushort_t* __restrict__ A, const ushort_t* __restrict__ W,
    const float* __restrict__ bias, float* __restrict__ o32) {
  __shared__ __align__(16) ushort_t As[2][128 * 32];
  __shared__ __align__(16) ushort_t Bs[2][128 * 32];
  const int tid = threadIdx.x;
  const int wave = tid >> 6, lane = tid & 63;
  const int wm = wave >> 1, wn = wave & 1;
  const int bm = blockIdx.y * 128, bn = blockIdx.x * 128;
  const int K = DMODEL;
  const int fr = lane & 15, fq = lane >> 4;

  const int rT = tid >> 2;
  const int cT = ((tid & 3) ^ (rT & 3)) << 3;
  const ushort_t* ag = A + (size_t)(bm + rT) * K + cT;
  const ushort_t* bg = W + (size_t)(bn + rT) * K + cT;

  floatx4 acc[4][4] = {};
  GSTAGE(0, 0);
  __syncthreads();
  for (int k0 = 0; k0 < K; k0 += 32) {
    const int cur = (k0 >> 5) & 1;
    if (k0 + 32 < K) GSTAGE(k0 + 32, cur ^ 1);
    const ushort_t* Ac = As[cur];
    const ushort_t* Bc = Bs[cur];
    bf16x8 af[4], bf[4];
#pragma unroll
    for (int i = 0; i < 4; i++)
      af[i] = *(const bf16x8*)(Ac + (wm * 64 + i * 16 + fr) * 32 + ((fq ^ (fr & 3)) << 3));
#pragma unroll
    for (int j = 0; j < 4; j++)
      bf[j] = *(const bf16x8*)(Bc + (wn * 64 + j * 16 + fr) * 32 + ((fq ^ (fr & 3)) << 3));
#pragma unroll
    for (int i = 0; i < 4; i++)
#pragma unroll
      for (int j = 0; j < 4; j++)
        acc[i][j] = mfma16(af[i], bf[j], acc[i][j]);
    __syncthreads();
  }

#pragma unroll
  for (int i = 0; i < 4; i++)
#pragma unroll
    for (int j = 0; j < 4; j++)
#pragma unroll
      for (int r = 0; r < 4; r++) {
        int m = bm + wm * 64 + i * 16 + fq * 4 + r;
        int n = bn + wn * 64 + j * 16 + fr;
        o32[(size_t)m * DMODEL + n] = acc[i][j][r] + bias[n];
      }
}

// Flash attention. Block = 128 q-rows x (b,h); wave w owns 32 q-rows.
// Fast path (mask==0): p = exp2(sc) directly — the uniform max-shift cancels in
// O = sum(p v)/sum(p), and sc <= ~12 << 127 so no overflow. No max reduce, no
// alpha, no rescale; l is a lane-partial reduced once at the end.
// P' LDS layout: row rho, position p stored at rho*64 + ((p>>3 ^ (rho&7))<<3) + (p&7),
// where p-order is the sigma-permuted key order baked into Vt. Lane's 4 score
// values -> one b64 write; reads are b128 at the LDS BW floor.
__global__ __launch_bounds__(256, 3) void flash_attn(
    const ushort_t* __restrict__ Qh, const ushort_t* __restrict__ Kh,
    const ushort_t* __restrict__ Vt, const float* __restrict__ mask,
    const int* __restrict__ mask_is_zero, ushort_t* __restrict__ Oh) {
  __shared__ __align__(16) ushort_t Ks[2][64 * 64];
  __shared__ __align__(16) ushort_t Vs[2][64 * 64];
  __shared__ __align__(16) ushort_t Ps[4][32 * 64];
  const int qt = blockIdx.x, bh = blockIdx.y;
  const int b = bh / NHEADS, h = bh % NHEADS;
  const int tid = threadIdx.x, w = tid >> 6, lane = tid & 63;
  const int li = lane & 15, lg = lane >> 4, sx = li & 7;
  const bool use_mask = (*mask_is_zero == 0);

  const int q0 = qt * 128 + w * 32;
  const ushort_t* qg = Qh + ((size_t)bh * S_LEN + q0) * DHEAD;
  bf16x8 qf[2][2];
#pragma unroll
  for (int m = 0; m < 2; m++)
#pragma unroll
    for (int kk = 0; kk < 2; kk++)
      qf[m][kk] = *(const bf16x8*)(qg + (m * 16 + li) * 64 + kk * 32 + lg * 8);

  const int srow = lane >> 3;
  const int schk = (lane & 7) ^ srow;
  const ushort_t* kg = Kh + (size_t)bh * S_LEN * DHEAD;
  const ushort_t* vg = Vt + (size_t)bh * DHEAD * S_LEN;

  float m_i[2][4], l_p[2][4];
  floatx4 o_acc[2][4] = {};
#pragma unroll
  for (int m = 0; m < 2; m++)
#pragma unroll
    for (int r = 0; r < 4; r++) { m_i[m][r] = -1e30f; l_p[m][r] = 0.f; }

#define STAGE(KT, BUF)                                                            \
  {                                                                               \
    const ushort_t* k0_ = kg + (size_t)((KT)*64 + w * 16 + srow) * 64 + schk * 8; \
    gld16(k0_, (char*)Ks + (BUF)*8192 + w * 2048);                                \
    gld16(k0_ + 8 * 64, (char*)Ks + (BUF)*8192 + w * 2048 + 1024);                \
    const ushort_t* v0_ = vg + (size_t)(w * 16 + srow) * 2048 + (KT)*64 + schk * 8; \
    gld16(v0_, (char*)Vs + (BUF)*8192 + w * 2048);                                \
    gld16(v0_ + 8 * 2048, (char*)Vs + (BUF)*8192 + w * 2048 + 1024);              \
  }

  STAGE(0, 0);
  __syncthreads();

  for (int kt = 0; kt < S_LEN / 64; kt++) {
    const int cur = kt & 1;
    if (kt < S_LEN / 64 - 1) STAGE(kt + 1, cur ^ 1);
    const ushort_t* Kc = Ks[cur];
    const ushort_t* Vc = Vs[cur];

    // S' = Q @ K^T (exp2-domain scale folded into Q)
    floatx4 sc[2][4];
#pragma unroll
    for (int c = 0; c < 4; c++) {
      bf16x8 kf0 = *(const bf16x8*)(Kc + (c * 16 + li) * 64 + ((lg ^ sx) << 3));
      bf16x8 kf1 = *(const bf16x8*)(Kc + (c * 16 + li) * 64 + (((4 + lg) ^ sx) << 3));
#pragma unroll
      for (int m = 0; m < 2; m++) {
        floatx4 s = {};
        s = mfma16(qf[m][0], kf0, s);
        s = mfma16(qf[m][1], kf1, s);
        sc[m][c] = s;
      }
    }

    if (!use_mask) {
      // fast path: no max shift needed (scores bounded, shift cancels exactly)
#pragma unroll
      for (int m = 0; m < 2; m++)
#pragma unroll
        for (int r = 0; r < 4; r++) {
          float s0 = fexp2(sc[m][0][r]);
          float s1 = fexp2(sc[m][1][r]);
          float s2 = fexp2(sc[m][2][r]);
          float s3 = fexp2(sc[m][3][r]);
          sc[m][0][r] = s0; sc[m][1][r] = s1; sc[m][2][r] = s2; sc[m][3][r] = s3;
          l_p[m][r] += (s0 + s1) + (s2 + s3);
        }
    } else {
      // general-mask fallback: running max + rescale (wave-uniform branch)
#pragma unroll
      for (int m = 0; m < 2; m++)
#pragma unroll
        for (int r = 0; r < 4; r++) {
          const float* mrow =
              mask + (size_t)(q0 + m * 16 + lg * 4 + r) * S_LEN + kt * 64;
#pragma unroll
          for (int c = 0; c < 4; c++) sc[m][c][r] += mrow[c * 16 + li] * LOG2E;
        }
      float alpha[4];
#pragma unroll
      for (int m = 0; m < 2; m++) {
#pragma unroll
        for (int r = 0; r < 4; r++) {
          float t = fmaxf(fmaxf(sc[m][0][r], sc[m][1][r]),
                          fmaxf(sc[m][2][r], sc[m][3][r]));
#pragma unroll
          for (int d = 1; d < 16; d <<= 1) t = fmaxf(t, __shfl_xor(t, d));
          float mn = fmaxf(m_i[m][r], t);
          alpha[r] = fexp2(m_i[m][r] - mn);
          m_i[m][r] = mn;
          float s0 = fexp2(sc[m][0][r] - mn);
          float s1 = fexp2(sc[m][1][r] - mn);
          float s2 = fexp2(sc[m][2][r] - mn);
          float s3 = fexp2(sc[m][3][r] - mn);
          sc[m][0][r] = s0; sc[m][1][r] = s1; sc[m][2][r] = s2; sc[m][3][r] = s3;
          l_p[m][r] = l_p[m][r] * alpha[r] + (s0 + s1) + (s2 + s3);
        }
#pragma unroll
        for (int dt = 0; dt < 4; dt++)
#pragma unroll
          for (int r = 0; r < 4; r++) o_acc[m][dt][r] *= alpha[r];
      }
    }

    // P' write: lane's 4 c-values are consecutive positions p = li*4+c -> b64
    ushort_t* pw = Ps[w];
#pragma unroll
    for (int m = 0; m < 2; m++)
#pragma unroll
      for (int r = 0; r < 4; r++) {
        int rho = m * 16 + lg * 4 + r;
        uint2 pv;
        pv.x = pk2bf(sc[m][0][r], sc[m][1][r]);
        pv.y = pk2bf(sc[m][2][r], sc[m][3][r]);
        *(uint2*)(pw + rho * 64 + ((((li >> 1) ^ (rho & 7)) << 3) | ((li & 1) << 2))) = pv;
      }

    // O += P @ V (k-dim in sigma-permuted p-order, matching Vt layout)
#pragma unroll
    for (int kk = 0; kk < 2; kk++) {
      bf16x8 pf[2];
#pragma unroll
      for (int m = 0; m < 2; m++)
        pf[m] = *(const bf16x8*)(pw + (m * 16 + li) * 64 + (((kk * 4 + lg) ^ sx) << 3));
#pragma unroll
      for (int dt = 0; dt < 4; dt++) {
        bf16x8 vf = *(const bf16x8*)(Vc + (dt * 16 + li) * 64 + (((kk * 4 + lg) ^ sx) << 3));
#pragma unroll
        for (int m = 0; m < 2; m++) o_acc[m][dt] = mfma16(pf[m], vf, o_acc[m][dt]);
      }
    }
    __syncthreads();
  }

  // epilogue: reduce lane-partial l over the 16-lane row group, write O
#pragma unroll
  for (int m = 0; m < 2; m++)
#pragma unroll
    for (int r = 0; r < 4; r++) {
      float l = l_p[m][r];
#pragma unroll
      for (int d = 1; d < 16; d <<= 1) l += __shfl_xor(l, d);
      float inv = 1.0f / l;
      int row = q0 + m * 16 + lg * 4 + r;
      ushort_t* ob = Oh + ((size_t)b * S_LEN + row) * DMODEL + h * DHEAD;
#pragma unroll
      for (int dt = 0; dt < 4; dt++) ob[dt * 16 + li] = f2bf(o_acc[m][dt][r] * inv);
    }
}

extern "C" void kernel_launch(void* const* d_in, const int* in_sizes, int n_in,
                              void* d_out, int out_size, void* d_ws, size_t ws_size,
                              hipStream_t stream) {
  const float* x = (const float*)d_in[0];
  const float* y = (const float*)d_in[1];
  const float* mask = (const float*)d_in[2];
  const float* Wq = (const float*)d_in[3];
  const float* bq = (const float*)d_in[4];
  const float* Wkv = (const float*)d_in[5];
  const float* bkv = (const float*)d_in[6];
  const float* Wo = (const float*)d_in[7];
  const float* bo = (const float*)d_in[8];
  float* out = (float*)d_out;

  ushort_t* ws = (ushort_t*)d_ws;
  const size_t XN = (size_t)BATCH * S_LEN * DMODEL;  // 6,291,456
  ushort_t* xb = ws;
  ushort_t* yb = xb + XN;
  ushort_t* wqb = yb + XN;
  ushort_t* wkvb = wqb + (size_t)DMODEL * DMODEL;
  ushort_t* wob = wkvb + (size_t)2 * DMODEL * DMODEL;
  ushort_t* Qh = wob + (size_t)DMODEL * DMODEL;
  ushort_t* Kh = Qh + XN;
  ushort_t* Vt = Kh + XN;
  int* flag = (int*)(Vt + XN);
  ushort_t* Oh = xb;  // alias: xb dead after Q-projection

  init_flag<<<1, 1, 0, stream>>>(flag);
  cvt_mask<<<18688, 256, 0, stream>>>(x, xb, y, yb, Wq, wqb, Wkv, wkvb, Wo, wob,
                                      mask, flag);
  gemm_qkv<<<dim3(18, 64), 256, 0, stream>>>(xb, wqb, bq, Qh, yb, wkvb, bkv, Kh, Vt);
  flash_attn<<<dim3(S_LEN / 128, BATCH * NHEADS), 256, 0, stream>>>(Qh, Kh, Vt, mask,
                                                                    flag, Oh);
  gemm_out<<<dim3(6, 64), 256, 0, stream>>>(Oh, wob, bo, out);
}

// Round 4
// 270.777 us; speedup vs baseline: 1.5695x; 1.0493x over previous
//
#include <hip/hip_runtime.h>
#include <cstdint>

#define S_LEN 2048
#define BATCH 4
#define NHEADS 12
#define DHEAD 64
#define DMODEL 768
#define SCALE_LOG2E 0.18033688011112042f  // (1/sqrt(64)) * log2(e)
#define LOG2E 1.4426950408889634f

typedef unsigned short ushort_t;
typedef __attribute__((ext_vector_type(8))) __bf16 bf16x8;
typedef __attribute__((ext_vector_type(4))) float floatx4;

// fp32 -> bf16 round-to-nearest-even (finite values only)
__device__ __forceinline__ ushort_t f2bf(float f) {
  unsigned u = __builtin_bit_cast(unsigned, f);
  u += 0x7fffu + ((u >> 16) & 1u);
  return (ushort_t)(u >> 16);
}

// pack two fp32 -> two bf16 (RTNE): a -> low16, b -> high16
#if __has_builtin(__builtin_amdgcn_cvt_pk_bf16_f32)
__device__ __forceinline__ unsigned pk2bf(float a, float b) {
  auto v = __builtin_amdgcn_cvt_pk_bf16_f32(a, b);
  return __builtin_bit_cast(unsigned, v);
}
#else
__device__ __forceinline__ unsigned pk2bf(float a, float b) {
  unsigned ua = __builtin_bit_cast(unsigned, a);
  unsigned ub = __builtin_bit_cast(unsigned, b);
  ua += 0x7fffu + ((ua >> 16) & 1u);
  ub += 0x7fffu + ((ub >> 16) & 1u);
  return __builtin_amdgcn_perm(ub, ua, 0x07060302);
}
#endif

__device__ __forceinline__ float fexp2(float x) {
#if __has_builtin(__builtin_amdgcn_exp2f)
  return __builtin_amdgcn_exp2f(x);
#else
  return exp2f(x);
#endif
}

// async global->LDS, 16B/lane. LDS dest is wave-uniform base; HW adds lane*16.
__device__ __forceinline__ void gld16(const void* g, void* s) {
  __builtin_amdgcn_global_load_lds(
      (const __attribute__((address_space(1))) void*)g,
      (__attribute__((address_space(3))) void*)s, 16, 0, 0);
}

__device__ __forceinline__ floatx4 mfma16(bf16x8 a, bf16x8 b, floatx4 c) {
  return __builtin_amdgcn_mfma_f32_16x16x32_bf16(a, b, c, 0, 0, 0);
}

// fused: bf16 conversion of all 5 fp32 tensors + mask-zero check (one launch)
__global__ void cvt_mask(const float* __restrict__ x, ushort_t* __restrict__ xb,
                         const float* __restrict__ y, ushort_t* __restrict__ yb,
                         const float* __restrict__ wq, ushort_t* __restrict__ wqb,
                         const float* __restrict__ wkv, ushort_t* __restrict__ wkvb,
                         const float* __restrict__ wo, ushort_t* __restrict__ wob,
                         const float* __restrict__ mask, int* __restrict__ flag) {
  int bx = blockIdx.x;
  if (bx >= 14592) {  // 4096 mask-check blocks (S*S/4 floats)
    int i = (bx - 14592) * 256 + threadIdx.x;
    float4 v = ((const float4*)mask)[i];
    if (v.x != 0.f || v.y != 0.f || v.z != 0.f || v.w != 0.f) *flag = 0;
    return;
  }
  const float* s;
  ushort_t* d;
  int base;
  if (bx < 6144) { s = x; d = xb; base = bx; }
  else if (bx < 12288) { s = y; d = yb; base = bx - 6144; }
  else if (bx < 12864) { s = wq; d = wqb; base = bx - 12288; }
  else if (bx < 14016) { s = wkv; d = wkvb; base = bx - 12864; }
  else { s = wo; d = wob; base = bx - 14016; }
  int i = base * 256 + threadIdx.x;
  float4 v = ((const float4*)s)[i];
  uint2 o;
  o.x = pk2bf(v.x, v.y);
  o.y = pk2bf(v.z, v.w);
  ((uint2*)d)[i] = o;
}

#define GSTAGE(K0, BUF)                                                   \
  {                                                                       \
    gld16(ag + (K0), (char*)As + (BUF)*8192 + (wave << 10));              \
    gld16(ag + (K0) + 64 * K, (char*)As + (BUF)*8192 + (wave << 10) + 4096); \
    gld16(bg + (K0), (char*)Bs + (BUF)*8192 + (wave << 10));              \
    gld16(bg + (K0) + 64 * K, (char*)Bs + (BUF)*8192 + (wave << 10) + 4096); \
  }

// Fused Q + KV projection. grid (18, 64): bx<6 -> Q tile, else KV tile.
// Q out: (B,H,S,Dh) bf16, scaled by SCALE_LOG2E (softmax scale folded).
// KV out: K (B,H,S,Dh) bf16; V^T (B,H,Dh,S) bf16 with per-64 kappa-permuted
// key positions so flash's PV B-fragments need no transpose (see flash_attn).
__global__ __launch_bounds__(256, 3) void gemm_qkv(
    const ushort_t* __restrict__ xb, const ushort_t* __restrict__ wqb,
    const float* __restrict__ bq, ushort_t* __restrict__ Qh,
    const ushort_t* __restrict__ yb, const ushort_t* __restrict__ wkvb,
    const float* __restrict__ bkv, ushort_t* __restrict__ Kh,
    ushort_t* __restrict__ Vt) {
  __shared__ __align__(16) ushort_t As[2][128 * 32];
  __shared__ __align__(16) ushort_t Bs[2][128 * 32];
  const int tid = threadIdx.x;
  const int wave = tid >> 6, lane = tid & 63;
  const int wm = wave >> 1, wn = wave & 1;
  const bool isQ = blockIdx.x < 6;
  const int bn = (isQ ? blockIdx.x : blockIdx.x - 6) * 128;
  const int bm = blockIdx.y * 128;
  const ushort_t* A = isQ ? xb : yb;
  const ushort_t* W = isQ ? wqb : wkvb;
  const float* bias = isQ ? bq : bkv;
  const int K = DMODEL;
  const int fr = lane & 15, fq = lane >> 4;

  const int rT = tid >> 2;
  const int cT = ((tid & 3) ^ (rT & 3)) << 3;
  const ushort_t* ag = A + (size_t)(bm + rT) * K + cT;
  const ushort_t* bg = W + (size_t)(bn + rT) * K + cT;

  floatx4 acc[4][4] = {};
  GSTAGE(0, 0);
  __syncthreads();
  for (int k0 = 0; k0 < K; k0 += 32) {
    const int cur = (k0 >> 5) & 1;
    if (k0 + 32 < K) GSTAGE(k0 + 32, cur ^ 1);
    const ushort_t* Ac = As[cur];
    const ushort_t* Bc = Bs[cur];
    bf16x8 af[4], bf[4];
#pragma unroll
    for (int i = 0; i < 4; i++)
      af[i] = *(const bf16x8*)(Ac + (wm * 64 + i * 16 + fr) * 32 + ((fq ^ (fr & 3)) << 3));
#pragma unroll
    for (int j = 0; j < 4; j++)
      bf[j] = *(const bf16x8*)(Bc + (wn * 64 + j * 16 + fr) * 32 + ((fq ^ (fr & 3)) << 3));
#pragma unroll
    for (int i = 0; i < 4; i++)
#pragma unroll
      for (int j = 0; j < 4; j++)
        acc[i][j] = mfma16(af[i], bf[j], acc[i][j]);
    __syncthreads();
  }

#pragma unroll
  for (int i = 0; i < 4; i++) {
#pragma unroll
    for (int j = 0; j < 4; j++) {
#pragma unroll
      for (int r = 0; r < 4; r++) {
        int m = bm + wm * 64 + i * 16 + fq * 4 + r;
        int n = bn + wn * 64 + j * 16 + fr;
        float v = acc[i][j][r] + bias[n];
        int b = m >> 11, s = m & 2047;
        if (isQ) {
          int h = n >> 6, d = n & 63;
          Qh[(((size_t)b * NHEADS + h) * S_LEN + s) * DHEAD + d] = f2bf(v * SCALE_LOG2E);
        } else {
          int h = n >> 7, jj = n & 127;
          if (jj < 64) {
            Kh[(((size_t)b * NHEADS + h) * S_LEN + s) * DHEAD + jj] = f2bf(v);
          } else {
            int s6 = s & 63;  // kappa-permute key position within 64-block
            int sp = (s & ~63) | ((s6 & 2) << 4) | (((s6 >> 2) & 3) << 3) |
                     ((s6 & 1) << 2) | (s6 >> 4);
            Vt[(((size_t)b * NHEADS + h) * DHEAD + (jj - 64)) * S_LEN + sp] = f2bf(v);
          }
        }
      }
    }
  }
}

// Output projection: C[M,768] fp32 = Oh @ Wo^T + bo.
__global__ __launch_bounds__(256, 3) void gemm_out(
    const ushort_t* __restrict__ A, const ushort_t* __restrict__ W,
    const float* __restrict__ bias, float* __restrict__ o32) {
  __shared__ __align__(16) ushort_t As[2][128 * 32];
  __shared__ __align__(16) ushort_t Bs[2][128 * 32];
  const int tid = threadIdx.x;
  const int wave = tid >> 6, lane = tid & 63;
  const int wm = wave >> 1, wn = wave & 1;
  const int bm = blockIdx.y * 128, bn = blockIdx.x * 128;
  const int K = DMODEL;
  const int fr = lane & 15, fq = lane >> 4;

  const int rT = tid >> 2;
  const int cT = ((tid & 3) ^ (rT & 3)) << 3;
  const ushort_t* ag = A + (size_t)(bm + rT) * K + cT;
  const ushort_t* bg = W + (size_t)(bn + rT) * K + cT;

  floatx4 acc[4][4] = {};
  GSTAGE(0, 0);
  __syncthreads();
  for (int k0 = 0; k0 < K; k0 += 32) {
    const int cur = (k0 >> 5) & 1;
    if (k0 + 32 < K) GSTAGE(k0 + 32, cur ^ 1);
    const ushort_t* Ac = As[cur];
    const ushort_t* Bc = Bs[cur];
    bf16x8 af[4], bf[4];
#pragma unroll
    for (int i = 0; i < 4; i++)
      af[i] = *(const bf16x8*)(Ac + (wm * 64 + i * 16 + fr) * 32 + ((fq ^ (fr & 3)) << 3));
#pragma unroll
    for (int j = 0; j < 4; j++)
      bf[j] = *(const bf16x8*)(Bc + (wn * 64 + j * 16 + fr) * 32 + ((fq ^ (fr & 3)) << 3));
#pragma unroll
    for (int i = 0; i < 4; i++)
#pragma unroll
      for (int j = 0; j < 4; j++)
        acc[i][j] = mfma16(af[i], bf[j], acc[i][j]);
    __syncthreads();
  }

#pragma unroll
  for (int i = 0; i < 4; i++)
#pragma unroll
    for (int j = 0; j < 4; j++)
#pragma unroll
      for (int r = 0; r < 4; r++) {
        int m = bm + wm * 64 + i * 16 + fq * 4 + r;
        int n = bn + wn * 64 + j * 16 + fr;
        o32[(size_t)m * DMODEL + n] = acc[i][j][r] + bias[n];
      }
}

// Flash attention, transposed: S^T = K@Q^T (C-layout col=q), O^T = V^T@P^T.
// S^T's C-layout IS the PV B-operand layout under the kappa key-permutation
// baked into Vt — no P transpose, no P LDS round-trip. Softmax is per-lane
// (each lane owns a full q-column's 16 keys of the 64-key tile).
// Fast path (mask==0): p = exp2(sc) directly — uniform shift cancels in the
// normalized sum; scores bounded << 127 so no overflow.
// Grid: 1-D 768, swizzled so the 16 q-tiles of one (b,h) share an XCD.
__global__ __launch_bounds__(256, 3) void flash_attn(
    const ushort_t* __restrict__ Qh, const ushort_t* __restrict__ Kh,
    const ushort_t* __restrict__ Vt, const float* __restrict__ mask,
    const int* __restrict__ mask_is_zero, ushort_t* __restrict__ Oh) {
  __shared__ __align__(16) ushort_t Ks[2][64 * 64];
  __shared__ __align__(16) ushort_t Vs[2][64 * 64];
  const int g = blockIdx.x;
  const int qt = (g >> 3) & 15;                 // q-tile
  const int bh = ((g >> 7) << 3) | (g & 7);     // (b,h); blocks of same bh -> same XCD
  const int b = bh / NHEADS, h = bh % NHEADS;
  const int tid = threadIdx.x, w = tid >> 6, lane = tid & 63;
  const int li = lane & 15, lg = lane >> 4, sx = li & 7;
  const bool use_mask = (*mask_is_zero == 0);

  // Q fragments (B-operand): lane holds Q[m*16+li][kk*32+lg*8 ..+8]
  const int q0 = qt * 128 + w * 32;
  const ushort_t* qg = Qh + ((size_t)bh * S_LEN + q0) * DHEAD;
  bf16x8 qf[2][2];
#pragma unroll
  for (int m = 0; m < 2; m++)
#pragma unroll
    for (int kk = 0; kk < 2; kk++)
      qf[m][kk] = *(const bf16x8*)(qg + (m * 16 + li) * 64 + kk * 32 + lg * 8);

  const int srow = lane >> 3;
  const int schk = (lane & 7) ^ srow;
  const ushort_t* kg = Kh + (size_t)bh * S_LEN * DHEAD;
  const ushort_t* vg = Vt + (size_t)bh * DHEAD * S_LEN;

  float m_i[2], l_pq[2];
  floatx4 o_accT[4][2] = {};  // [d-tile][q-tile]: O^T, col=q=li, row=d=lg*4+r
#pragma unroll
  for (int m = 0; m < 2; m++) { m_i[m] = -1e30f; l_pq[m] = 0.f; }

#define STAGE(KT, BUF)                                                            \
  {                                                                               \
    const ushort_t* k0_ = kg + (size_t)((KT)*64 + w * 16 + srow) * 64 + schk * 8; \
    gld16(k0_, (char*)Ks + (BUF)*8192 + w * 2048);                                \
    gld16(k0_ + 8 * 64, (char*)Ks + (BUF)*8192 + w * 2048 + 1024);                \
    const ushort_t* v0_ = vg + (size_t)(w * 16 + srow) * 2048 + (KT)*64 + schk * 8; \
    gld16(v0_, (char*)Vs + (BUF)*8192 + w * 2048);                                \
    gld16(v0_ + 8 * 2048, (char*)Vs + (BUF)*8192 + w * 2048 + 1024);              \
  }

  STAGE(0, 0);
  __syncthreads();

  for (int kt = 0; kt < S_LEN / 64; kt++) {
    const int cur = kt & 1;
    if (kt < S_LEN / 64 - 1) STAGE(kt + 1, cur ^ 1);
    const ushort_t* Kc = Ks[cur];
    const ushort_t* Vc = Vs[cur];

    // S^T = K @ Q^T: sc[m][c][r] = score(q = q0+m*16+li, key = c*16+lg*4+r)
    floatx4 sc[2][4];
#pragma unroll
    for (int c = 0; c < 4; c++) {
      bf16x8 kf0 = *(const bf16x8*)(Kc + (c * 16 + li) * 64 + ((lg ^ sx) << 3));
      bf16x8 kf1 = *(const bf16x8*)(Kc + (c * 16 + li) * 64 + (((4 + lg) ^ sx) << 3));
#pragma unroll
      for (int m = 0; m < 2; m++) {
        floatx4 s = {};
        s = mfma16(kf0, qf[m][0], s);
        s = mfma16(kf1, qf[m][1], s);
        sc[m][c] = s;
      }
    }

    bf16x8 pf[2][2];  // PV B-fragments, packed in-register
    if (!use_mask) {
#pragma unroll
      for (int m = 0; m < 2; m++) {
        float cs[4];
#pragma unroll
        for (int c = 0; c < 4; c++) {
          float e0 = fexp2(sc[m][c][0]);
          float e1 = fexp2(sc[m][c][1]);
          float e2 = fexp2(sc[m][c][2]);
          float e3 = fexp2(sc[m][c][3]);
          sc[m][c][0] = e0; sc[m][c][1] = e1; sc[m][c][2] = e2; sc[m][c][3] = e3;
          cs[c] = (e0 + e1) + (e2 + e3);
        }
        l_pq[m] += (cs[0] + cs[1]) + (cs[2] + cs[3]);
      }
    } else {
      // general-mask fallback (wave-uniform branch): running max + rescale
#pragma unroll
      for (int m = 0; m < 2; m++) {
        int q = q0 + m * 16 + li;
#pragma unroll
        for (int c = 0; c < 4; c++) {
          float4 mv = *(const float4*)(mask + (size_t)q * S_LEN + kt * 64 + c * 16 + lg * 4);
          sc[m][c][0] += mv.x * LOG2E;
          sc[m][c][1] += mv.y * LOG2E;
          sc[m][c][2] += mv.z * LOG2E;
          sc[m][c][3] += mv.w * LOG2E;
        }
        float mx = sc[m][0][0];
#pragma unroll
        for (int c = 0; c < 4; c++)
#pragma unroll
          for (int r = 0; r < 4; r++) mx = fmaxf(mx, sc[m][c][r]);
        mx = fmaxf(mx, __shfl_xor(mx, 16));
        mx = fmaxf(mx, __shfl_xor(mx, 32));
        float mn = fmaxf(m_i[m], mx);
        float al = fexp2(m_i[m] - mn);
        m_i[m] = mn;
        float cs[4];
#pragma unroll
        for (int c = 0; c < 4; c++) {
          float e0 = fexp2(sc[m][c][0] - mn);
          float e1 = fexp2(sc[m][c][1] - mn);
          float e2 = fexp2(sc[m][c][2] - mn);
          float e3 = fexp2(sc[m][c][3] - mn);
          sc[m][c][0] = e0; sc[m][c][1] = e1; sc[m][c][2] = e2; sc[m][c][3] = e3;
          cs[c] = (e0 + e1) + (e2 + e3);
        }
        l_pq[m] = l_pq[m] * al + (cs[0] + cs[1]) + (cs[2] + cs[3]);
#pragma unroll
        for (int dt = 0; dt < 4; dt++)
#pragma unroll
          for (int r = 0; r < 4; r++) o_accT[dt][m][r] *= al;
      }
    }

    // pack P^T B-frags: tile kk slot j = sc[m][j&3][2*kk + (j>>2)]
#pragma unroll
    for (int m = 0; m < 2; m++)
#pragma unroll
      for (int kk = 0; kk < 2; kk++) {
        uint4 u;
        u.x = pk2bf(sc[m][0][2 * kk], sc[m][1][2 * kk]);
        u.y = pk2bf(sc[m][2][2 * kk], sc[m][3][2 * kk]);
        u.z = pk2bf(sc[m][0][2 * kk + 1], sc[m][1][2 * kk + 1]);
        u.w = pk2bf(sc[m][2][2 * kk + 1], sc[m][3][2 * kk + 1]);
        pf[m][kk] = __builtin_bit_cast(bf16x8, u);
      }

    // O^T += V^T @ P^T (k = kappa-permuted key positions, matching Vt layout)
#pragma unroll
    for (int kk = 0; kk < 2; kk++)
#pragma unroll
      for (int dt = 0; dt < 4; dt++) {
        bf16x8 vf = *(const bf16x8*)(Vc + (dt * 16 + li) * 64 + (((kk * 4 + lg) ^ sx) << 3));
#pragma unroll
        for (int m = 0; m < 2; m++) o_accT[dt][m] = mfma16(vf, pf[m][kk], o_accT[dt][m]);
      }
    __syncthreads();
  }

  // epilogue: l is lane-partial over the lane's 16 keys; reduce across the
  // 4 lane-groups (xor 16/32), then write O^T transposed to (B,S,H*Dh).
#pragma unroll
  for (int m = 0; m < 2; m++) {
    float l = l_pq[m];
    l += __shfl_xor(l, 16);
    l += __shfl_xor(l, 32);
    float inv = 1.0f / l;
    int q = q0 + m * 16 + li;
    ushort_t* ob = Oh + ((size_t)b * S_LEN + q) * DMODEL + h * DHEAD + lg * 4;
#pragma unroll
    for (int dt = 0; dt < 4; dt++) {
      uint2 pv;
      pv.x = pk2bf(o_accT[dt][m][0] * inv, o_accT[dt][m][1] * inv);
      pv.y = pk2bf(o_accT[dt][m][2] * inv, o_accT[dt][m][3] * inv);
      *(uint2*)(ob + dt * 16) = pv;
    }
  }
}

extern "C" void kernel_launch(void* const* d_in, const int* in_sizes, int n_in,
                              void* d_out, int out_size, void* d_ws, size_t ws_size,
                              hipStream_t stream) {
  const float* x = (const float*)d_in[0];
  const float* y = (const float*)d_in[1];
  const float* mask = (const float*)d_in[2];
  const float* Wq = (const float*)d_in[3];
  const float* bq = (const float*)d_in[4];
  const float* Wkv = (const float*)d_in[5];
  const float* bkv = (const float*)d_in[6];
  const float* Wo = (const float*)d_in[7];
  const float* bo = (const float*)d_in[8];
  float* out = (float*)d_out;

  ushort_t* ws = (ushort_t*)d_ws;
  const size_t XN = (size_t)BATCH * S_LEN * DMODEL;  // 6,291,456
  ushort_t* xb = ws;
  ushort_t* yb = xb + XN;
  ushort_t* wqb = yb + XN;
  ushort_t* wkvb = wqb + (size_t)DMODEL * DMODEL;
  ushort_t* wob = wkvb + (size_t)2 * DMODEL * DMODEL;
  ushort_t* Qh = wob + (size_t)DMODEL * DMODEL;
  ushort_t* Kh = Qh + XN;
  ushort_t* Vt = Kh + XN;
  int* flag = (int*)(Vt + XN);
  ushort_t* Oh = xb;  // alias: xb dead after Q-projection

  hipMemsetAsync(flag, 1, 4, stream);  // nonzero init; cvt_mask clears if mask!=0
  cvt_mask<<<18688, 256, 0, stream>>>(x, xb, y, yb, Wq, wqb, Wkv, wkvb, Wo, wob,
                                      mask, flag);
  gemm_qkv<<<dim3(18, 64), 256, 0, stream>>>(xb, wqb, bq, Qh, yb, wkvb, bkv, Kh, Vt);
  flash_attn<<<768, 256, 0, stream>>>(Qh, Kh, Vt, mask, flag, Oh);
  gemm_out<<<dim3(6, 64), 256, 0, stream>>>(Oh, wob, bo, out);
}

// Round 5
// 256.668 us; speedup vs baseline: 1.6557x; 1.0550x over previous
//
#include <hip/hip_runtime.h>
#include <cstdint>

#define S_LEN 2048
#define BATCH 4
#define NHEADS 12
#define DHEAD 64
#define DMODEL 768
#define SCALE_LOG2E 0.18033688011112042f  // (1/sqrt(64)) * log2(e)
#define LOG2E 1.4426950408889634f

typedef unsigned short ushort_t;
typedef __attribute__((ext_vector_type(8))) __bf16 bf16x8;
typedef __attribute__((ext_vector_type(4))) float floatx4;

// fp32 -> bf16 round-to-nearest-even (finite values only)
__device__ __forceinline__ ushort_t f2bf(float f) {
  unsigned u = __builtin_bit_cast(unsigned, f);
  u += 0x7fffu + ((u >> 16) & 1u);
  return (ushort_t)(u >> 16);
}

// pack two fp32 -> two bf16 (RTNE): a -> low16, b -> high16
#if __has_builtin(__builtin_amdgcn_cvt_pk_bf16_f32)
__device__ __forceinline__ unsigned pk2bf(float a, float b) {
  auto v = __builtin_amdgcn_cvt_pk_bf16_f32(a, b);
  return __builtin_bit_cast(unsigned, v);
}
#else
__device__ __forceinline__ unsigned pk2bf(float a, float b) {
  unsigned ua = __builtin_bit_cast(unsigned, a);
  unsigned ub = __builtin_bit_cast(unsigned, b);
  ua += 0x7fffu + ((ua >> 16) & 1u);
  ub += 0x7fffu + ((ub >> 16) & 1u);
  return __builtin_amdgcn_perm(ub, ua, 0x07060302);
}
#endif

__device__ __forceinline__ float fexp2(float x) {
#if __has_builtin(__builtin_amdgcn_exp2f)
  return __builtin_amdgcn_exp2f(x);
#else
  return exp2f(x);
#endif
}

// async global->LDS, 16B/lane. LDS dest is wave-uniform base; HW adds lane*16.
__device__ __forceinline__ void gld16(const void* g, void* s) {
  __builtin_amdgcn_global_load_lds(
      (const __attribute__((address_space(1))) void*)g,
      (__attribute__((address_space(3))) void*)s, 16, 0, 0);
}

__device__ __forceinline__ floatx4 mfma16(bf16x8 a, bf16x8 b, floatx4 c) {
  return __builtin_amdgcn_mfma_f32_16x16x32_bf16(a, b, c, 0, 0, 0);
}

// fused: bf16 conversion of all 5 fp32 tensors + mask-zero check (one launch)
__global__ void cvt_mask(const float* __restrict__ x, ushort_t* __restrict__ xb,
                         const float* __restrict__ y, ushort_t* __restrict__ yb,
                         const float* __restrict__ wq, ushort_t* __restrict__ wqb,
                         const float* __restrict__ wkv, ushort_t* __restrict__ wkvb,
                         const float* __restrict__ wo, ushort_t* __restrict__ wob,
                         const float* __restrict__ mask, int* __restrict__ flag) {
  int bx = blockIdx.x;
  if (bx >= 14592) {  // 4096 mask-check blocks (S*S/4 floats)
    int i = (bx - 14592) * 256 + threadIdx.x;
    float4 v = ((const float4*)mask)[i];
    if (v.x != 0.f || v.y != 0.f || v.z != 0.f || v.w != 0.f) *flag = 0;
    return;
  }
  const float* s;
  ushort_t* d;
  int base;
  if (bx < 6144) { s = x; d = xb; base = bx; }
  else if (bx < 12288) { s = y; d = yb; base = bx - 6144; }
  else if (bx < 12864) { s = wq; d = wqb; base = bx - 12288; }
  else if (bx < 14016) { s = wkv; d = wkvb; base = bx - 12864; }
  else { s = wo; d = wob; base = bx - 14016; }
  int i = base * 256 + threadIdx.x;
  float4 v = ((const float4*)s)[i];
  uint2 o;
  o.x = pk2bf(v.x, v.y);
  o.y = pk2bf(v.z, v.w);
  ((uint2*)d)[i] = o;
}

#define GSTAGE(K0, BUF)                                                      \
  {                                                                          \
    gld16(ag + (K0), (char*)As + (BUF)*8192 + (wave << 10));                 \
    gld16(ag + (K0) + 64 * K, (char*)As + (BUF)*8192 + (wave << 10) + 4096); \
    gld16(bg + (K0), (char*)Bs + (BUF)*8192 + (wave << 10));                 \
    gld16(bg + (K0) + 64 * K, (char*)Bs + (BUF)*8192 + (wave << 10) + 4096); \
  }

// Fused Q + KV projection. 1-D grid 1152, XCD-swizzled: g&7 = XCD slot; each
// XCD owns 8 consecutive A-row tiles (by) x all 18 bx -> A + W fit its L2.
// Q out: (B,H,S,Dh) bf16, scaled by SCALE_LOG2E (softmax scale folded).
// KV out: K (B,H,S,Dh); V^T (B,H,Dh,S) with kappa key-permutation per 64-block
// (position p holds key: s[1:0]=p[1:0], s[3:2]=p[4:3], s[4]=p[2], s[5]=p[5]),
// written via LDS restage as coalesced 16B stores (256B/16-lane segments).
__global__ __launch_bounds__(256, 3) void gemm_qkv(
    const ushort_t* __restrict__ xb, const ushort_t* __restrict__ wqb,
    const float* __restrict__ bq, ushort_t* __restrict__ Qh,
    const ushort_t* __restrict__ yb, const ushort_t* __restrict__ wkvb,
    const float* __restrict__ bkv, ushort_t* __restrict__ Kh,
    ushort_t* __restrict__ Vt) {
  __shared__ __align__(16) ushort_t smem[2 * 4096 + 2 * 4096];  // 32 KB
  ushort_t* As = smem;         // [2][4096]
  ushort_t* Bs = smem + 8192;  // [2][4096]
  const int tid = threadIdx.x;
  const int wave = tid >> 6, lane = tid & 63;
  const int wm = wave >> 1, wn = wave & 1;
  const int g = blockIdx.x;
  const int r144 = g >> 3;
  const int by = (g & 7) * 8 + r144 / 18;
  const int bxr = r144 % 18;
  const bool isQ = bxr < 6;
  const int bn = (isQ ? bxr : bxr - 6) * 128;
  const int bm = by * 128;
  const ushort_t* A = isQ ? xb : yb;
  const ushort_t* W = isQ ? wqb : wkvb;
  const float* bias = isQ ? bq : bkv;
  const int K = DMODEL;
  const int fr = lane & 15, fq = lane >> 4;

  const int rT = tid >> 2;
  const int cT = ((tid & 3) ^ (rT & 3)) << 3;
  const ushort_t* ag = A + (size_t)(bm + rT) * K + cT;
  const ushort_t* bg = W + (size_t)(bn + rT) * K + cT;

  floatx4 acc[4][4] = {};
  GSTAGE(0, 0);
  __syncthreads();
  for (int k0 = 0; k0 < K; k0 += 32) {
    const int cur = (k0 >> 5) & 1;
    if (k0 + 32 < K) GSTAGE(k0 + 32, cur ^ 1);
    const ushort_t* Ac = As + cur * 4096;
    const ushort_t* Bc = Bs + cur * 4096;
    bf16x8 af[4], bf[4];
#pragma unroll
    for (int i = 0; i < 4; i++)
      af[i] = *(const bf16x8*)(Ac + (wm * 64 + i * 16 + fr) * 32 + ((fq ^ (fr & 3)) << 3));
#pragma unroll
    for (int j = 0; j < 4; j++)
      bf[j] = *(const bf16x8*)(Bc + (wn * 64 + j * 16 + fr) * 32 + ((fq ^ (fr & 3)) << 3));
#pragma unroll
    for (int i = 0; i < 4; i++)
#pragma unroll
      for (int j = 0; j < 4; j++)
        acc[i][j] = mfma16(af[i], bf[j], acc[i][j]);
    __syncthreads();
  }

  const int b = bm >> 11, sloc = bm & 2047;
  if (isQ) {
#pragma unroll
    for (int i = 0; i < 4; i++)
#pragma unroll
      for (int j = 0; j < 4; j++)
#pragma unroll
        for (int r = 0; r < 4; r++) {
          int m = bm + wm * 64 + i * 16 + fq * 4 + r;
          int n = bn + wn * 64 + j * 16 + fr;
          float v = acc[i][j][r] + bias[n];
          int s = m & 2047, h = n >> 6, d = n & 63;
          Qh[(((size_t)b * NHEADS + h) * S_LEN + s) * DHEAD + d] = f2bf(v * SCALE_LOG2E);
        }
  } else {
    const int h = bn >> 7;
    ushort_t* Vls = smem;  // [64][132] bf16, overlays As/Bs (dead after loop)
    if (wn == 0) {
      // K half: direct stores (32B-coalesced across fr)
#pragma unroll
      for (int i = 0; i < 4; i++)
#pragma unroll
        for (int j = 0; j < 4; j++)
#pragma unroll
          for (int r = 0; r < 4; r++) {
            int m = bm + wm * 64 + i * 16 + fq * 4 + r;
            int n = bn + j * 16 + fr;
            float v = acc[i][j][r] + bias[n];
            int s = m & 2047, jj = n & 127;
            Kh[(((size_t)b * NHEADS + h) * S_LEN + s) * DHEAD + jj] = f2bf(v);
          }
    } else {
      // V half: restage into LDS [d][m] (packed b64 writes)
#pragma unroll
      for (int j = 0; j < 4; j++) {
        int d = j * 16 + fr;
        float bv = bias[bn + 64 + j * 16 + fr];
#pragma unroll
        for (int i = 0; i < 4; i++) {
          int m = wm * 64 + i * 16 + fq * 4;
          uint2 pv;
          pv.x = pk2bf(acc[i][j][0] + bv, acc[i][j][1] + bv);
          pv.y = pk2bf(acc[i][j][2] + bv, acc[i][j][3] + bv);
          *(uint2*)(Vls + d * 132 + m) = pv;
        }
      }
    }
    __syncthreads();
    // all waves: V^T coalesced stores. Lane group of 16 covers one d-row's
    // 128 positions (2 blk x 8 octets); position p=oct*8+idx holds key
    // blk*64 + base + (idx<4 ? idx : 12+idx), base=(oct>>2)*32+(oct&3)*4.
    const int dbase = wave * 4 + (lane >> 4);
    const int blk = (lane >> 3) & 1, oct = lane & 7;
    const int kbase = blk * 64 + ((oct >> 2) << 5) + ((oct & 3) << 2);
    ushort_t* vout = Vt + (((size_t)b * NHEADS + h) * DHEAD) * S_LEN + sloc +
                     blk * 64 + oct * 8;
#pragma unroll
    for (int k = 0; k < 4; k++) {
      int dd = dbase + k * 16;
      uint2 lo = *(const uint2*)(Vls + dd * 132 + kbase);
      uint2 hi = *(const uint2*)(Vls + dd * 132 + kbase + 16);
      uint4 u = {lo.x, lo.y, hi.x, hi.y};
      *(uint4*)(vout + (size_t)dd * S_LEN) = u;
    }
  }
}

// Output projection: C[M,768] fp32 = Oh @ Wo^T + bo. 64x128 tiles, grid 768
// (3 blocks/CU), XCD-swizzled (16 by-tiles per XCD), double-buffered LDS.
__global__ __launch_bounds__(256, 4) void gemm_out(
    const ushort_t* __restrict__ A, const ushort_t* __restrict__ W,
    const float* __restrict__ bias, float* __restrict__ o32) {
  __shared__ __align__(16) ushort_t As[2][64 * 32];
  __shared__ __align__(16) ushort_t Bs[2][128 * 32];
  const int tid = threadIdx.x;
  const int wave = tid >> 6, lane = tid & 63;
  const int wm = wave >> 1, wn = wave & 1;
  const int g = blockIdx.x;
  const int r96 = g >> 3;
  const int bm = ((g & 7) * 16 + r96 / 6) * 64;
  const int bn = (r96 % 6) * 128;
  const int K = DMODEL;
  const int fr = lane & 15, fq = lane >> 4;

  const int rT = tid >> 2;
  const int cT = ((tid & 3) ^ (rT & 3)) << 3;
  const ushort_t* ag = A + (size_t)(bm + rT) * K + cT;  // rT 0..63
  const ushort_t* bg = W + (size_t)(bn + rT) * K + cT;

#define GOSTAGE(K0, BUF)                                                     \
  {                                                                          \
    gld16(ag + (K0), (char*)As + (BUF)*4096 + (wave << 10));                 \
    gld16(bg + (K0), (char*)Bs + (BUF)*8192 + (wave << 10));                 \
    gld16(bg + (K0) + 64 * K, (char*)Bs + (BUF)*8192 + (wave << 10) + 4096); \
  }

  floatx4 acc[2][4] = {};
  GOSTAGE(0, 0);
  __syncthreads();
  for (int k0 = 0; k0 < K; k0 += 32) {
    const int cur = (k0 >> 5) & 1;
    if (k0 + 32 < K) GOSTAGE(k0 + 32, cur ^ 1);
    const ushort_t* Ac = (const ushort_t*)As + cur * 2048;
    const ushort_t* Bc = (const ushort_t*)Bs + cur * 4096;
    bf16x8 af[2], bf[4];
#pragma unroll
    for (int i = 0; i < 2; i++)
      af[i] = *(const bf16x8*)(Ac + (wm * 32 + i * 16 + fr) * 32 + ((fq ^ (fr & 3)) << 3));
#pragma unroll
    for (int j = 0; j < 4; j++)
      bf[j] = *(const bf16x8*)(Bc + (wn * 64 + j * 16 + fr) * 32 + ((fq ^ (fr & 3)) << 3));
#pragma unroll
    for (int i = 0; i < 2; i++)
#pragma unroll
      for (int j = 0; j < 4; j++)
        acc[i][j] = mfma16(af[i], bf[j], acc[i][j]);
    __syncthreads();
  }

#pragma unroll
  for (int i = 0; i < 2; i++)
#pragma unroll
    for (int j = 0; j < 4; j++)
#pragma unroll
      for (int r = 0; r < 4; r++) {
        int m = bm + wm * 32 + i * 16 + fq * 4 + r;
        int n = bn + wn * 64 + j * 16 + fr;
        o32[(size_t)m * DMODEL + n] = acc[i][j][r] + bias[n];
      }
}

// Flash attention, transposed: S^T = K@Q^T (C-layout col=q), O^T = V^T@P^T.
// S^T's C-layout IS the PV B-operand layout under the kappa key-permutation
// baked into Vt — no P transpose, no LDS round-trip. Softmax is per-lane.
// Fast path (mask==0): p = exp2(sc) directly — uniform shift cancels in the
// normalized sum; scores bounded << 127 so no overflow.
// Grid: 1-D 768, swizzled so the 16 q-tiles of one (b,h) share an XCD.
__global__ __launch_bounds__(256, 3) void flash_attn(
    const ushort_t* __restrict__ Qh, const ushort_t* __restrict__ Kh,
    const ushort_t* __restrict__ Vt, const float* __restrict__ mask,
    const int* __restrict__ mask_is_zero, ushort_t* __restrict__ Oh) {
  __shared__ __align__(16) ushort_t Ks[2][64 * 64];
  __shared__ __align__(16) ushort_t Vs[2][64 * 64];
  const int g = blockIdx.x;
  const int qt = (g >> 3) & 15;                 // q-tile
  const int bh = ((g >> 7) << 3) | (g & 7);     // (b,h); same bh -> same XCD
  const int b = bh / NHEADS, h = bh % NHEADS;
  const int tid = threadIdx.x, w = tid >> 6, lane = tid & 63;
  const int li = lane & 15, lg = lane >> 4, sx = li & 7;
  const bool use_mask = (*mask_is_zero == 0);

  // Q fragments (B-operand): lane holds Q[m*16+li][kk*32+lg*8 ..+8]
  const int q0 = qt * 128 + w * 32;
  const ushort_t* qg = Qh + ((size_t)bh * S_LEN + q0) * DHEAD;
  bf16x8 qf[2][2];
#pragma unroll
  for (int m = 0; m < 2; m++)
#pragma unroll
    for (int kk = 0; kk < 2; kk++)
      qf[m][kk] = *(const bf16x8*)(qg + (m * 16 + li) * 64 + kk * 32 + lg * 8);

  const int srow = lane >> 3;
  const int schk = (lane & 7) ^ srow;
  const ushort_t* kg = Kh + (size_t)bh * S_LEN * DHEAD;
  const ushort_t* vg = Vt + (size_t)bh * DHEAD * S_LEN;

  float m_i[2], l_pq[2];
  floatx4 o_accT[4][2] = {};  // [d-tile][q-tile]: O^T, col=q=li, row=d=lg*4+r
#pragma unroll
  for (int m = 0; m < 2; m++) { m_i[m] = -1e30f; l_pq[m] = 0.f; }

#define STAGE(KT, BUF)                                                            \
  {                                                                               \
    const ushort_t* k0_ = kg + (size_t)((KT)*64 + w * 16 + srow) * 64 + schk * 8; \
    gld16(k0_, (char*)Ks + (BUF)*8192 + w * 2048);                                \
    gld16(k0_ + 8 * 64, (char*)Ks + (BUF)*8192 + w * 2048 + 1024);                \
    const ushort_t* v0_ = vg + (size_t)(w * 16 + srow) * 2048 + (KT)*64 + schk * 8; \
    gld16(v0_, (char*)Vs + (BUF)*8192 + w * 2048);                                \
    gld16(v0_ + 8 * 2048, (char*)Vs + (BUF)*8192 + w * 2048 + 1024);              \
  }

  STAGE(0, 0);
  __syncthreads();

  for (int kt = 0; kt < S_LEN / 64; kt++) {
    const int cur = kt & 1;
    if (kt < S_LEN / 64 - 1) STAGE(kt + 1, cur ^ 1);
    const ushort_t* Kc = Ks[cur];
    const ushort_t* Vc = Vs[cur];

    // S^T = K @ Q^T: sc[m][c][r] = score(q = q0+m*16+li, key = c*16+lg*4+r)
    floatx4 sc[2][4];
#pragma unroll
    for (int c = 0; c < 4; c++) {
      bf16x8 kf0 = *(const bf16x8*)(Kc + (c * 16 + li) * 64 + ((lg ^ sx) << 3));
      bf16x8 kf1 = *(const bf16x8*)(Kc + (c * 16 + li) * 64 + (((4 + lg) ^ sx) << 3));
#pragma unroll
      for (int m = 0; m < 2; m++) {
        floatx4 s = {};
        s = mfma16(kf0, qf[m][0], s);
        s = mfma16(kf1, qf[m][1], s);
        sc[m][c] = s;
      }
    }

    if (!use_mask) {
#pragma unroll
      for (int m = 0; m < 2; m++) {
        float cs[4];
#pragma unroll
        for (int c = 0; c < 4; c++) {
          float e0 = fexp2(sc[m][c][0]);
          float e1 = fexp2(sc[m][c][1]);
          float e2 = fexp2(sc[m][c][2]);
          float e3 = fexp2(sc[m][c][3]);
          sc[m][c][0] = e0; sc[m][c][1] = e1; sc[m][c][2] = e2; sc[m][c][3] = e3;
          cs[c] = (e0 + e1) + (e2 + e3);
        }
        l_pq[m] += (cs[0] + cs[1]) + (cs[2] + cs[3]);
      }
    } else {
      // general-mask fallback (wave-uniform branch): running max + rescale
#pragma unroll
      for (int m = 0; m < 2; m++) {
        int q = q0 + m * 16 + li;
#pragma unroll
        for (int c = 0; c < 4; c++) {
          float4 mv = *(const float4*)(mask + (size_t)q * S_LEN + kt * 64 + c * 16 + lg * 4);
          sc[m][c][0] += mv.x * LOG2E;
          sc[m][c][1] += mv.y * LOG2E;
          sc[m][c][2] += mv.z * LOG2E;
          sc[m][c][3] += mv.w * LOG2E;
        }
        float mx = sc[m][0][0];
#pragma unroll
        for (int c = 0; c < 4; c++)
#pragma unroll
          for (int r = 0; r < 4; r++) mx = fmaxf(mx, sc[m][c][r]);
        mx = fmaxf(mx, __shfl_xor(mx, 16));
        mx = fmaxf(mx, __shfl_xor(mx, 32));
        float mn = fmaxf(m_i[m], mx);
        float al = fexp2(m_i[m] - mn);
        m_i[m] = mn;
        float cs[4];
#pragma unroll
        for (int c = 0; c < 4; c++) {
          float e0 = fexp2(sc[m][c][0] - mn);
          float e1 = fexp2(sc[m][c][1] - mn);
          float e2 = fexp2(sc[m][c][2] - mn);
          float e3 = fexp2(sc[m][c][3] - mn);
          sc[m][c][0] = e0; sc[m][c][1] = e1; sc[m][c][2] = e2; sc[m][c][3] = e3;
          cs[c] = (e0 + e1) + (e2 + e3);
        }
        l_pq[m] = l_pq[m] * al + (cs[0] + cs[1]) + (cs[2] + cs[3]);
#pragma unroll
        for (int dt = 0; dt < 4; dt++)
#pragma unroll
          for (int r = 0; r < 4; r++) o_accT[dt][m][r] *= al;
      }
    }

    // pack P^T B-frags: slot j of tile kk = sc[m][2*kk + (j>>2)][j&3]
    // (matches kappa: key(p) bits s[1:0]=p[1:0], s[3:2]=p[4:3], s[4]=p[2], s[5]=p[5])
    bf16x8 pf[2][2];
#pragma unroll
    for (int m = 0; m < 2; m++)
#pragma unroll
      for (int kk = 0; kk < 2; kk++) {
        uint4 u;
        u.x = pk2bf(sc[m][2 * kk][0], sc[m][2 * kk][1]);
        u.y = pk2bf(sc[m][2 * kk][2], sc[m][2 * kk][3]);
        u.z = pk2bf(sc[m][2 * kk + 1][0], sc[m][2 * kk + 1][1]);
        u.w = pk2bf(sc[m][2 * kk + 1][2], sc[m][2 * kk + 1][3]);
        pf[m][kk] = __builtin_bit_cast(bf16x8, u);
      }

    // O^T += V^T @ P^T (k = kappa-permuted key positions, matching Vt layout)
#pragma unroll
    for (int kk = 0; kk < 2; kk++)
#pragma unroll
      for (int dt = 0; dt < 4; dt++) {
        bf16x8 vf = *(const bf16x8*)(Vc + (dt * 16 + li) * 64 + (((kk * 4 + lg) ^ sx) << 3));
#pragma unroll
        for (int m = 0; m < 2; m++) o_accT[dt][m] = mfma16(vf, pf[m][kk], o_accT[dt][m]);
      }
    __syncthreads();
  }

  // epilogue: reduce lane-partial l across the 4 lane-groups, write O^T
  // transposed to (B,S,H*Dh) bf16.
#pragma unroll
  for (int m = 0; m < 2; m++) {
    float l = l_pq[m];
    l += __shfl_xor(l, 16);
    l += __shfl_xor(l, 32);
    float inv = 1.0f / l;
    int q = q0 + m * 16 + li;
    ushort_t* ob = Oh + ((size_t)b * S_LEN + q) * DMODEL + h * DHEAD + lg * 4;
#pragma unroll
    for (int dt = 0; dt < 4; dt++) {
      uint2 pv;
      pv.x = pk2bf(o_accT[dt][m][0] * inv, o_accT[dt][m][1] * inv);
      pv.y = pk2bf(o_accT[dt][m][2] * inv, o_accT[dt][m][3] * inv);
      *(uint2*)(ob + dt * 16) = pv;
    }
  }
}

extern "C" void kernel_launch(void* const* d_in, const int* in_sizes, int n_in,
                              void* d_out, int out_size, void* d_ws, size_t ws_size,
                              hipStream_t stream) {
  const float* x = (const float*)d_in[0];
  const float* y = (const float*)d_in[1];
  const float* mask = (const float*)d_in[2];
  const float* Wq = (const float*)d_in[3];
  const float* bq = (const float*)d_in[4];
  const float* Wkv = (const float*)d_in[5];
  const float* bkv = (const float*)d_in[6];
  const float* Wo = (const float*)d_in[7];
  const float* bo = (const float*)d_in[8];
  float* out = (float*)d_out;

  ushort_t* ws = (ushort_t*)d_ws;
  const size_t XN = (size_t)BATCH * S_LEN * DMODEL;  // 6,291,456
  ushort_t* xb = ws;
  ushort_t* yb = xb + XN;
  ushort_t* wqb = yb + XN;
  ushort_t* wkvb = wqb + (size_t)DMODEL * DMODEL;
  ushort_t* wob = wkvb + (size_t)2 * DMODEL * DMODEL;
  ushort_t* Qh = wob + (size_t)DMODEL * DMODEL;
  ushort_t* Kh = Qh + XN;
  ushort_t* Vt = Kh + XN;
  int* flag = (int*)(Vt + XN);
  ushort_t* Oh = xb;  // alias: xb dead after Q-projection

  hipMemsetAsync(flag, 1, 4, stream);  // nonzero init; cvt_mask clears if mask!=0
  cvt_mask<<<18688, 256, 0, stream>>>(x, xb, y, yb, Wq, wqb, Wkv, wkvb, Wo, wob,
                                      mask, flag);
  gemm_qkv<<<1152, 256, 0, stream>>>(xb, wqb, bq, Qh, yb, wkvb, bkv, Kh, Vt);
  flash_attn<<<768, 256, 0, stream>>>(Qh, Kh, Vt, mask, flag, Oh);
  gemm_out<<<768, 256, 0, stream>>>(Oh, wob, bo, out);
}

// Round 6
// 248.883 us; speedup vs baseline: 1.7075x; 1.0313x over previous
//
#include <hip/hip_runtime.h>
#include <cstdint>

#define S_LEN 2048
#define BATCH 4
#define NHEADS 12
#define DHEAD 64
#define DMODEL 768
#define SCALE_LOG2E 0.18033688011112042f  // (1/sqrt(64)) * log2(e)
#define LOG2E 1.4426950408889634f

typedef unsigned short ushort_t;
typedef __attribute__((ext_vector_type(8))) __bf16 bf16x8;
typedef __attribute__((ext_vector_type(4))) float floatx4;

// fp32 -> bf16 round-to-nearest-even (finite values only)
__device__ __forceinline__ ushort_t f2bf(float f) {
  unsigned u = __builtin_bit_cast(unsigned, f);
  u += 0x7fffu + ((u >> 16) & 1u);
  return (ushort_t)(u >> 16);
}

// pack two fp32 -> two bf16 (RTNE): a -> low16, b -> high16
#if __has_builtin(__builtin_amdgcn_cvt_pk_bf16_f32)
__device__ __forceinline__ unsigned pk2bf(float a, float b) {
  auto v = __builtin_amdgcn_cvt_pk_bf16_f32(a, b);
  return __builtin_bit_cast(unsigned, v);
}
#else
__device__ __forceinline__ unsigned pk2bf(float a, float b) {
  unsigned ua = __builtin_bit_cast(unsigned, a);
  unsigned ub = __builtin_bit_cast(unsigned, b);
  ua += 0x7fffu + ((ua >> 16) & 1u);
  ub += 0x7fffu + ((ub >> 16) & 1u);
  return __builtin_amdgcn_perm(ub, ua, 0x07060302);
}
#endif

__device__ __forceinline__ float fexp2(float x) {
#if __has_builtin(__builtin_amdgcn_exp2f)
  return __builtin_amdgcn_exp2f(x);
#else
  return exp2f(x);
#endif
}

// async global->LDS, 16B/lane. LDS dest is wave-uniform base; HW adds lane*16.
__device__ __forceinline__ void gld16(const void* g, void* s) {
  __builtin_amdgcn_global_load_lds(
      (const __attribute__((address_space(1))) void*)g,
      (__attribute__((address_space(3))) void*)s, 16, 0, 0);
}

__device__ __forceinline__ floatx4 mfma16(bf16x8 a, bf16x8 b, floatx4 c) {
  return __builtin_amdgcn_mfma_f32_16x16x32_bf16(a, b, c, 0, 0, 0);
}

// fused: bf16 conversion of all 5 fp32 tensors + mask-zero check (one launch)
__global__ void cvt_mask(const float* __restrict__ x, ushort_t* __restrict__ xb,
                         const float* __restrict__ y, ushort_t* __restrict__ yb,
                         const float* __restrict__ wq, ushort_t* __restrict__ wqb,
                         const float* __restrict__ wkv, ushort_t* __restrict__ wkvb,
                         const float* __restrict__ wo, ushort_t* __restrict__ wob,
                         const float* __restrict__ mask, int* __restrict__ flag) {
  int bx = blockIdx.x;
  if (bx >= 14592) {  // 4096 mask-check blocks (S*S/4 floats)
    int i = (bx - 14592) * 256 + threadIdx.x;
    float4 v = ((const float4*)mask)[i];
    if (v.x != 0.f || v.y != 0.f || v.z != 0.f || v.w != 0.f) *flag = 0;
    return;
  }
  const float* s;
  ushort_t* d;
  int base;
  if (bx < 6144) { s = x; d = xb; base = bx; }
  else if (bx < 12288) { s = y; d = yb; base = bx - 6144; }
  else if (bx < 12864) { s = wq; d = wqb; base = bx - 12288; }
  else if (bx < 14016) { s = wkv; d = wkvb; base = bx - 12864; }
  else { s = wo; d = wob; base = bx - 14016; }
  int i = base * 256 + threadIdx.x;
  float4 v = ((const float4*)s)[i];
  uint2 o;
  o.x = pk2bf(v.x, v.y);
  o.y = pk2bf(v.z, v.w);
  ((uint2*)d)[i] = o;
}

#define GSTAGE(K0, BUF)                                                      \
  {                                                                          \
    gld16(ag + (K0), (char*)As + (BUF)*8192 + (wave << 10));                 \
    gld16(ag + (K0) + 64 * K, (char*)As + (BUF)*8192 + (wave << 10) + 4096); \
    gld16(bg + (K0), (char*)Bs + (BUF)*8192 + (wave << 10));                 \
    gld16(bg + (K0) + 64 * K, (char*)Bs + (BUF)*8192 + (wave << 10) + 4096); \
  }

// Fused Q + KV projection. 1-D grid 1152, XCD-swizzled: g&7 = XCD slot; each
// XCD owns 8 consecutive A-row tiles (by) x all 18 bx -> A + W fit its L2.
// Q out: (B,H,S,Dh) bf16, scaled by SCALE_LOG2E (softmax scale folded).
// KV out: K (B,H,S,Dh); V^T (B,H,Dh,S) with kappa key-permutation per 64-block
// (position p holds key: s[1:0]=p[1:0], s[3:2]=p[4:3], s[4]=p[2], s[5]=p[5]),
// written via LDS restage as coalesced 16B stores (256B/16-lane segments).
__global__ __launch_bounds__(256, 4) void gemm_qkv(
    const ushort_t* __restrict__ xb, const ushort_t* __restrict__ wqb,
    const float* __restrict__ bq, ushort_t* __restrict__ Qh,
    const ushort_t* __restrict__ yb, const ushort_t* __restrict__ wkvb,
    const float* __restrict__ bkv, ushort_t* __restrict__ Kh,
    ushort_t* __restrict__ Vt) {
  __shared__ __align__(16) ushort_t smem[2 * 4096 + 2 * 4096];  // 32 KB
  ushort_t* As = smem;         // [2][4096]
  ushort_t* Bs = smem + 8192;  // [2][4096]
  const int tid = threadIdx.x;
  const int wave = tid >> 6, lane = tid & 63;
  const int wm = wave >> 1, wn = wave & 1;
  const int g = blockIdx.x;
  const int r144 = g >> 3;
  const int by = (g & 7) * 8 + r144 / 18;
  const int bxr = r144 % 18;
  const bool isQ = bxr < 6;
  const int bn = (isQ ? bxr : bxr - 6) * 128;
  const int bm = by * 128;
  const ushort_t* A = isQ ? xb : yb;
  const ushort_t* W = isQ ? wqb : wkvb;
  const float* bias = isQ ? bq : bkv;
  const int K = DMODEL;
  const int fr = lane & 15, fq = lane >> 4;

  const int rT = tid >> 2;
  const int cT = ((tid & 3) ^ (rT & 3)) << 3;
  const ushort_t* ag = A + (size_t)(bm + rT) * K + cT;
  const ushort_t* bg = W + (size_t)(bn + rT) * K + cT;

  floatx4 acc[4][4] = {};
  GSTAGE(0, 0);
  __syncthreads();
  for (int k0 = 0; k0 < K; k0 += 32) {
    const int cur = (k0 >> 5) & 1;
    if (k0 + 32 < K) GSTAGE(k0 + 32, cur ^ 1);
    const ushort_t* Ac = As + cur * 4096;
    const ushort_t* Bc = Bs + cur * 4096;
    bf16x8 af[4], bf[4];
#pragma unroll
    for (int i = 0; i < 4; i++)
      af[i] = *(const bf16x8*)(Ac + (wm * 64 + i * 16 + fr) * 32 + ((fq ^ (fr & 3)) << 3));
#pragma unroll
    for (int j = 0; j < 4; j++)
      bf[j] = *(const bf16x8*)(Bc + (wn * 64 + j * 16 + fr) * 32 + ((fq ^ (fr & 3)) << 3));
#pragma unroll
    for (int i = 0; i < 4; i++)
#pragma unroll
      for (int j = 0; j < 4; j++)
        acc[i][j] = mfma16(af[i], bf[j], acc[i][j]);
    __syncthreads();
  }

  const int b = bm >> 11, sloc = bm & 2047;
  if (isQ) {
#pragma unroll
    for (int i = 0; i < 4; i++)
#pragma unroll
      for (int j = 0; j < 4; j++)
#pragma unroll
        for (int r = 0; r < 4; r++) {
          int m = bm + wm * 64 + i * 16 + fq * 4 + r;
          int n = bn + wn * 64 + j * 16 + fr;
          float v = acc[i][j][r] + bias[n];
          int s = m & 2047, h = n >> 6, d = n & 63;
          Qh[(((size_t)b * NHEADS + h) * S_LEN + s) * DHEAD + d] = f2bf(v * SCALE_LOG2E);
        }
  } else {
    const int h = bn >> 7;
    ushort_t* Vls = smem;  // [64][132] bf16, overlays As/Bs (dead after loop)
    if (wn == 0) {
      // K half: direct stores (32B-coalesced across fr)
#pragma unroll
      for (int i = 0; i < 4; i++)
#pragma unroll
        for (int j = 0; j < 4; j++)
#pragma unroll
          for (int r = 0; r < 4; r++) {
            int m = bm + wm * 64 + i * 16 + fq * 4 + r;
            int n = bn + j * 16 + fr;
            float v = acc[i][j][r] + bias[n];
            int s = m & 2047, jj = n & 127;
            Kh[(((size_t)b * NHEADS + h) * S_LEN + s) * DHEAD + jj] = f2bf(v);
          }
    } else {
      // V half: restage into LDS [d][m] (packed b64 writes)
#pragma unroll
      for (int j = 0; j < 4; j++) {
        int d = j * 16 + fr;
        float bv = bias[bn + 64 + j * 16 + fr];
#pragma unroll
        for (int i = 0; i < 4; i++) {
          int m = wm * 64 + i * 16 + fq * 4;
          uint2 pv;
          pv.x = pk2bf(acc[i][j][0] + bv, acc[i][j][1] + bv);
          pv.y = pk2bf(acc[i][j][2] + bv, acc[i][j][3] + bv);
          *(uint2*)(Vls + d * 132 + m) = pv;
        }
      }
    }
    __syncthreads();
    // all waves: V^T coalesced stores. Lane group of 16 covers one d-row's
    // 128 positions (2 blk x 8 octets); position p=oct*8+idx holds key
    // blk*64 + base + (idx<4 ? idx : 12+idx), base=(oct>>2)*32+(oct&3)*4.
    const int dbase = wave * 4 + (lane >> 4);
    const int blk = (lane >> 3) & 1, oct = lane & 7;
    const int kbase = blk * 64 + ((oct >> 2) << 5) + ((oct & 3) << 2);
    ushort_t* vout = Vt + (((size_t)b * NHEADS + h) * DHEAD) * S_LEN + sloc +
                     blk * 64 + oct * 8;
#pragma unroll
    for (int k = 0; k < 4; k++) {
      int dd = dbase + k * 16;
      uint2 lo = *(const uint2*)(Vls + dd * 132 + kbase);
      uint2 hi = *(const uint2*)(Vls + dd * 132 + kbase + 16);
      uint4 u = {lo.x, lo.y, hi.x, hi.y};
      *(uint4*)(vout + (size_t)dd * S_LEN) = u;
    }
  }
}

// Output projection: C[M,768] fp32 = Oh @ Wo^T + bo. 64x128 tiles, grid 768
// (3 blocks/CU), XCD-swizzled (16 by-tiles per XCD), double-buffered LDS.
__global__ __launch_bounds__(256, 4) void gemm_out(
    const ushort_t* __restrict__ A, const ushort_t* __restrict__ W,
    const float* __restrict__ bias, float* __restrict__ o32) {
  __shared__ __align__(16) ushort_t As[2][64 * 32];
  __shared__ __align__(16) ushort_t Bs[2][128 * 32];
  const int tid = threadIdx.x;
  const int wave = tid >> 6, lane = tid & 63;
  const int wm = wave >> 1, wn = wave & 1;
  const int g = blockIdx.x;
  const int r96 = g >> 3;
  const int bm = ((g & 7) * 16 + r96 / 6) * 64;
  const int bn = (r96 % 6) * 128;
  const int K = DMODEL;
  const int fr = lane & 15, fq = lane >> 4;

  const int rT = tid >> 2;
  const int cT = ((tid & 3) ^ (rT & 3)) << 3;
  const ushort_t* ag = A + (size_t)(bm + rT) * K + cT;  // rT 0..63
  const ushort_t* bg = W + (size_t)(bn + rT) * K + cT;

#define GOSTAGE(K0, BUF)                                                     \
  {                                                                          \
    gld16(ag + (K0), (char*)As + (BUF)*4096 + (wave << 10));                 \
    gld16(bg + (K0), (char*)Bs + (BUF)*8192 + (wave << 10));                 \
    gld16(bg + (K0) + 64 * K, (char*)Bs + (BUF)*8192 + (wave << 10) + 4096); \
  }

  floatx4 acc[2][4] = {};
  GOSTAGE(0, 0);
  __syncthreads();
  for (int k0 = 0; k0 < K; k0 += 32) {
    const int cur = (k0 >> 5) & 1;
    if (k0 + 32 < K) GOSTAGE(k0 + 32, cur ^ 1);
    const ushort_t* Ac = (const ushort_t*)As + cur * 2048;
    const ushort_t* Bc = (const ushort_t*)Bs + cur * 4096;
    bf16x8 af[2], bf[4];
#pragma unroll
    for (int i = 0; i < 2; i++)
      af[i] = *(const bf16x8*)(Ac + (wm * 32 + i * 16 + fr) * 32 + ((fq ^ (fr & 3)) << 3));
#pragma unroll
    for (int j = 0; j < 4; j++)
      bf[j] = *(const bf16x8*)(Bc + (wn * 64 + j * 16 + fr) * 32 + ((fq ^ (fr & 3)) << 3));
#pragma unroll
    for (int i = 0; i < 2; i++)
#pragma unroll
      for (int j = 0; j < 4; j++)
        acc[i][j] = mfma16(af[i], bf[j], acc[i][j]);
    __syncthreads();
  }

#pragma unroll
  for (int i = 0; i < 2; i++)
#pragma unroll
    for (int j = 0; j < 4; j++)
#pragma unroll
      for (int r = 0; r < 4; r++) {
        int m = bm + wm * 32 + i * 16 + fq * 4 + r;
        int n = bn + wn * 64 + j * 16 + fr;
        o32[(size_t)m * DMODEL + n] = acc[i][j][r] + bias[n];
      }
}

// Flash attention, transposed: S^T = K@Q^T (C-layout col=q), O^T = V^T@P^T.
// S^T's C-layout IS the PV B-operand layout under the kappa key-permutation
// baked into Vt — no P transpose, no LDS round-trip. Softmax is per-lane.
// Row-sum l computed by MFMA with A = ones (register constant): every lane's
// acc slots hold l[q=li] — no VALU sums, no epilogue shuffle reduce.
// Fast path (mask==0): p = exp2(sc) directly — uniform shift cancels in the
// normalized sum; scores bounded << 127 so no overflow.
// Grid: 1-D 768, swizzled so the 16 q-tiles of one (b,h) share an XCD.
__global__ __launch_bounds__(256, 3) void flash_attn(
    const ushort_t* __restrict__ Qh, const ushort_t* __restrict__ Kh,
    const ushort_t* __restrict__ Vt, const float* __restrict__ mask,
    const int* __restrict__ mask_is_zero, ushort_t* __restrict__ Oh) {
  __shared__ __align__(16) ushort_t Ks[2][64 * 64];
  __shared__ __align__(16) ushort_t Vs[2][64 * 64];
  const int g = blockIdx.x;
  const int qt = (g >> 3) & 15;                 // q-tile
  const int bh = ((g >> 7) << 3) | (g & 7);     // (b,h); same bh -> same XCD
  const int b = bh / NHEADS, h = bh % NHEADS;
  const int tid = threadIdx.x, w = tid >> 6, lane = tid & 63;
  const int li = lane & 15, lg = lane >> 4, sx = li & 7;
  const bool use_mask = (*mask_is_zero == 0);

  // all-ones A-fragment (bf16 1.0 in every slot) for the l-row-sum MFMA
  const unsigned one2 = 0x3F803F80u;
  const uint4 onesu = {one2, one2, one2, one2};
  const bf16x8 onesf = __builtin_bit_cast(bf16x8, onesu);

  // Q fragments (B-operand): lane holds Q[m*16+li][kk*32+lg*8 ..+8]
  const int q0 = qt * 128 + w * 32;
  const ushort_t* qg = Qh + ((size_t)bh * S_LEN + q0) * DHEAD;
  bf16x8 qf[2][2];
#pragma unroll
  for (int m = 0; m < 2; m++)
#pragma unroll
    for (int kk = 0; kk < 2; kk++)
      qf[m][kk] = *(const bf16x8*)(qg + (m * 16 + li) * 64 + kk * 32 + lg * 8);

  const int srow = lane >> 3;
  const int schk = (lane & 7) ^ srow;
  const ushort_t* kg = Kh + (size_t)bh * S_LEN * DHEAD;
  const ushort_t* vg = Vt + (size_t)bh * DHEAD * S_LEN;

  float m_i[2];
  floatx4 o_accT[4][2] = {};  // [d-tile][q-tile]: O^T, col=q=li, row=d=lg*4+r
  floatx4 l_acc[2] = {};      // l[q=li] in every slot (ones-MFMA accumulator)
#pragma unroll
  for (int m = 0; m < 2; m++) m_i[m] = -1e30f;

#define STAGE(KT, BUF)                                                            \
  {                                                                               \
    const ushort_t* k0_ = kg + (size_t)((KT)*64 + w * 16 + srow) * 64 + schk * 8; \
    gld16(k0_, (char*)Ks + (BUF)*8192 + w * 2048);                                \
    gld16(k0_ + 8 * 64, (char*)Ks + (BUF)*8192 + w * 2048 + 1024);                \
    const ushort_t* v0_ = vg + (size_t)(w * 16 + srow) * 2048 + (KT)*64 + schk * 8; \
    gld16(v0_, (char*)Vs + (BUF)*8192 + w * 2048);                                \
    gld16(v0_ + 8 * 2048, (char*)Vs + (BUF)*8192 + w * 2048 + 1024);              \
  }

  STAGE(0, 0);
  __syncthreads();

  for (int kt = 0; kt < S_LEN / 64; kt++) {
    const int cur = kt & 1;
    if (kt < S_LEN / 64 - 1) STAGE(kt + 1, cur ^ 1);
    const ushort_t* Kc = Ks[cur];
    const ushort_t* Vc = Vs[cur];

    // S^T = K @ Q^T: sc[m][c][r] = score(q = q0+m*16+li, key = c*16+lg*4+r)
    floatx4 sc[2][4];
#pragma unroll
    for (int c = 0; c < 4; c++) {
      bf16x8 kf0 = *(const bf16x8*)(Kc + (c * 16 + li) * 64 + ((lg ^ sx) << 3));
      bf16x8 kf1 = *(const bf16x8*)(Kc + (c * 16 + li) * 64 + (((4 + lg) ^ sx) << 3));
#pragma unroll
      for (int m = 0; m < 2; m++) {
        floatx4 s = {};
        s = mfma16(kf0, qf[m][0], s);
        s = mfma16(kf1, qf[m][1], s);
        sc[m][c] = s;
      }
    }

    if (!use_mask) {
      // fast path: exponentiate only — sums come from the ones-MFMA below
#pragma unroll
      for (int m = 0; m < 2; m++)
#pragma unroll
        for (int c = 0; c < 4; c++) {
          sc[m][c][0] = fexp2(sc[m][c][0]);
          sc[m][c][1] = fexp2(sc[m][c][1]);
          sc[m][c][2] = fexp2(sc[m][c][2]);
          sc[m][c][3] = fexp2(sc[m][c][3]);
        }
    } else {
      // general-mask fallback (wave-uniform branch): running max + rescale
#pragma unroll
      for (int m = 0; m < 2; m++) {
        int q = q0 + m * 16 + li;
#pragma unroll
        for (int c = 0; c < 4; c++) {
          float4 mv = *(const float4*)(mask + (size_t)q * S_LEN + kt * 64 + c * 16 + lg * 4);
          sc[m][c][0] += mv.x * LOG2E;
          sc[m][c][1] += mv.y * LOG2E;
          sc[m][c][2] += mv.z * LOG2E;
          sc[m][c][3] += mv.w * LOG2E;
        }
        float mx = sc[m][0][0];
#pragma unroll
        for (int c = 0; c < 4; c++)
#pragma unroll
          for (int r = 0; r < 4; r++) mx = fmaxf(mx, sc[m][c][r]);
        mx = fmaxf(mx, __shfl_xor(mx, 16));
        mx = fmaxf(mx, __shfl_xor(mx, 32));
        float mn = fmaxf(m_i[m], mx);
        float al = fexp2(m_i[m] - mn);
        m_i[m] = mn;
#pragma unroll
        for (int c = 0; c < 4; c++) {
          sc[m][c][0] = fexp2(sc[m][c][0] - mn);
          sc[m][c][1] = fexp2(sc[m][c][1] - mn);
          sc[m][c][2] = fexp2(sc[m][c][2] - mn);
          sc[m][c][3] = fexp2(sc[m][c][3] - mn);
        }
#pragma unroll
        for (int r = 0; r < 4; r++) l_acc[m][r] *= al;
#pragma unroll
        for (int dt = 0; dt < 4; dt++)
#pragma unroll
          for (int r = 0; r < 4; r++) o_accT[dt][m][r] *= al;
      }
    }

    // pack P^T B-frags: slot j of tile kk = sc[m][2*kk + (j>>2)][j&3]
    // (matches kappa: key(p) bits s[1:0]=p[1:0], s[3:2]=p[4:3], s[4]=p[2], s[5]=p[5])
    bf16x8 pf[2][2];
#pragma unroll
    for (int m = 0; m < 2; m++)
#pragma unroll
      for (int kk = 0; kk < 2; kk++) {
        uint4 u;
        u.x = pk2bf(sc[m][2 * kk][0], sc[m][2 * kk][1]);
        u.y = pk2bf(sc[m][2 * kk][2], sc[m][2 * kk][3]);
        u.z = pk2bf(sc[m][2 * kk + 1][0], sc[m][2 * kk + 1][1]);
        u.w = pk2bf(sc[m][2 * kk + 1][2], sc[m][2 * kk + 1][3]);
        pf[m][kk] = __builtin_bit_cast(bf16x8, u);
      }

    // l += ones @ P^T  (row-sum on the matrix pipe; A is a register constant)
#pragma unroll
    for (int m = 0; m < 2; m++)
#pragma unroll
      for (int kk = 0; kk < 2; kk++)
        l_acc[m] = mfma16(onesf, pf[m][kk], l_acc[m]);

    // O^T += V^T @ P^T (k = kappa-permuted key positions, matching Vt layout)
#pragma unroll
    for (int kk = 0; kk < 2; kk++)
#pragma unroll
      for (int dt = 0; dt < 4; dt++) {
        bf16x8 vf = *(const bf16x8*)(Vc + (dt * 16 + li) * 64 + (((kk * 4 + lg) ^ sx) << 3));
#pragma unroll
        for (int m = 0; m < 2; m++) o_accT[dt][m] = mfma16(vf, pf[m][kk], o_accT[dt][m]);
      }
    __syncthreads();
  }

  // epilogue: l[q] already complete in every lane's l_acc slots — no reduce.
#pragma unroll
  for (int m = 0; m < 2; m++) {
    float inv = 1.0f / l_acc[m][0];
    int q = q0 + m * 16 + li;
    ushort_t* ob = Oh + ((size_t)b * S_LEN + q) * DMODEL + h * DHEAD + lg * 4;
#pragma unroll
    for (int dt = 0; dt < 4; dt++) {
      uint2 pv;
      pv.x = pk2bf(o_accT[dt][m][0] * inv, o_accT[dt][m][1] * inv);
      pv.y = pk2bf(o_accT[dt][m][2] * inv, o_accT[dt][m][3] * inv);
      *(uint2*)(ob + dt * 16) = pv;
    }
  }
}

extern "C" void kernel_launch(void* const* d_in, const int* in_sizes, int n_in,
                              void* d_out, int out_size, void* d_ws, size_t ws_size,
                              hipStream_t stream) {
  const float* x = (const float*)d_in[0];
  const float* y = (const float*)d_in[1];
  const float* mask = (const float*)d_in[2];
  const float* Wq = (const float*)d_in[3];
  const float* bq = (const float*)d_in[4];
  const float* Wkv = (const float*)d_in[5];
  const float* bkv = (const float*)d_in[6];
  const float* Wo = (const float*)d_in[7];
  const float* bo = (const float*)d_in[8];
  float* out = (float*)d_out;

  ushort_t* ws = (ushort_t*)d_ws;
  const size_t XN = (size_t)BATCH * S_LEN * DMODEL;  // 6,291,456
  ushort_t* xb = ws;
  ushort_t* yb = xb + XN;
  ushort_t* wqb = yb + XN;
  ushort_t* wkvb = wqb + (size_t)DMODEL * DMODEL;
  ushort_t* wob = wkvb + (size_t)2 * DMODEL * DMODEL;
  ushort_t* Qh = wob + (size_t)DMODEL * DMODEL;
  ushort_t* Kh = Qh + XN;
  ushort_t* Vt = Kh + XN;
  int* flag = (int*)(Vt + XN);
  ushort_t* Oh = xb;  // alias: xb dead after Q-projection

  hipMemsetAsync(flag, 1, 4, stream);  // nonzero init; cvt_mask clears if mask!=0
  cvt_mask<<<18688, 256, 0, stream>>>(x, xb, y, yb, Wq, wqb, Wkv, wkvb, Wo, wob,
                                      mask, flag);
  gemm_qkv<<<1152, 256, 0, stream>>>(xb, wqb, bq, Qh, yb, wkvb, bkv, Kh, Vt);
  flash_attn<<<768, 256, 0, stream>>>(Qh, Kh, Vt, mask, flag, Oh);
  gemm_out<<<768, 256, 0, stream>>>(Oh, wob, bo, out);
}